// Round 1
// baseline (2034.903 us; speedup 1.0000x reference)
//
#include <hip/hip_runtime.h>
#include <cmath>

#define L_SEQ 2048
#define BATCH 8
#define CIN 256
#define DIN 512
#define M_ROWS (BATCH * L_SEQ)  // 16384

// ---------------- transpose (B,C,L) -> (B,L,C) ----------------
__global__ __launch_bounds__(256) void transpose_in(const float* __restrict__ in,
                                                    float* __restrict__ out) {
  __shared__ float tile[32][33];
  int b = blockIdx.z;
  int l0 = blockIdx.x * 32, c0 = blockIdx.y * 32;
  int tx = threadIdx.x, ty = threadIdx.y;  // 32 x 8
#pragma unroll
  for (int k = 0; k < 4; ++k)
    tile[ty + k * 8][tx] = in[(long)(b * CIN + c0 + ty + k * 8) * L_SEQ + l0 + tx];
  __syncthreads();
#pragma unroll
  for (int k = 0; k < 4; ++k)
    out[(long)(b * L_SEQ + l0 + ty + k * 8) * CIN + c0 + tx] = tile[tx][ty + k * 8];
}

// ---------------- fp32 SIMT GEMM:  C[m,n] = sum_k A[m,k] * W[n,k] ----------------
// EPI 0: plain store   EPI 1: softplus(v + bias[n])   EPI 2: relu(v+bias) + scatter to (spk,b,c,l)
template <int EPI>
__global__ __launch_bounds__(256) void gemm_f32(const float* __restrict__ A, int lda,
                                                const float* __restrict__ W,
                                                float* __restrict__ C, int ldc, int N, int K,
                                                const float* __restrict__ bias) {
  __shared__ float As[16][65];
  __shared__ float Ws[16][65];
  int tid = threadIdx.x;
  int tx = tid & 15, ty = tid >> 4;
  int m0 = blockIdx.y * 64, n0 = blockIdx.x * 64;
  float acc[4][4] = {};
  for (int k0 = 0; k0 < K; k0 += 16) {
#pragma unroll
    for (int r = 0; r < 4; ++r) {
      int p = tid + r * 256;
      int i = p >> 4, k = p & 15;
      As[k][i] = A[(long)(m0 + i) * lda + k0 + k];
      float wv = 0.f;
      if (n0 + i < N) wv = W[(long)(n0 + i) * K + k0 + k];
      Ws[k][i] = wv;
    }
    __syncthreads();
#pragma unroll
    for (int kk = 0; kk < 16; ++kk) {
      float ar[4], br[4];
#pragma unroll
      for (int i = 0; i < 4; ++i) ar[i] = As[kk][(EPI == 2 ? tx : ty) + i * 16];
#pragma unroll
      for (int j = 0; j < 4; ++j) br[j] = Ws[kk][(EPI == 2 ? ty : tx) + j * 16];
#pragma unroll
      for (int i = 0; i < 4; ++i)
#pragma unroll
        for (int j = 0; j < 4; ++j) acc[i][j] += ar[i] * br[j];
    }
    __syncthreads();
  }
#pragma unroll
  for (int i = 0; i < 4; ++i) {
#pragma unroll
    for (int j = 0; j < 4; ++j) {
      if (EPI == 2) {
        int m = m0 + tx + i * 16;
        int n = n0 + ty + j * 16;
        if (n < N) {
          float v = acc[i][j] + bias[n];
          v = v > 0.f ? v : 0.f;
          int b = m >> 11, l = m & 2047;
          int spk = n >> 8, c = n & 255;
          C[(((long)(spk * BATCH + b)) * CIN + c) * L_SEQ + l] = v;
        }
      } else {
        int m = m0 + ty + i * 16;
        int n = n0 + tx + j * 16;
        if (n < N) {
          float v = acc[i][j];
          if (EPI == 1) {
            v += bias[n];
            v = (v > 20.f) ? v : log1pf(__expf(v));
          }
          C[(long)m * ldc + n] = v;
        }
      }
    }
  }
}

// ---------------- depthwise causal conv(4) + bias + SiLU ----------------
__global__ __launch_bounds__(256) void conv_silu(const float* __restrict__ xz,
                                                 const float* __restrict__ cw,
                                                 const float* __restrict__ cb,
                                                 float* __restrict__ xc) {
  int idx = blockIdx.x * 256 + threadIdx.x;  // over M_ROWS*512
  int d = idx & 511;
  int ml = idx >> 9;
  int l = ml & 2047;
  float acc = cb[d];
  const float* w = cw + d * 4;
#pragma unroll
  for (int k = 0; k < 4; ++k) {
    int ll = l + k - 3;
    if (ll >= 0) acc += w[k] * xz[(long)(ml + k - 3) * 1024 + d];
  }
  xc[(long)ml * 512 + d] = acc / (1.f + __expf(-acc));
}

// ---------------- selective scan ----------------
// thread (b, d, s): s = tid&15, dlocal = tid>>4 ; block = (16 d) x (16 s); grid (DIN/16, B)
// reads delta (=buf_dy), xc, x_db (B,C cols), z (xz cols 512..); writes y in-place over delta.
#define TS 32
__global__ __launch_bounds__(256) void scan_kernel(const float* __restrict__ delta,
                                                   float* __restrict__ y,
                                                   const float* __restrict__ xc,
                                                   const float* __restrict__ xdb,
                                                   const float* __restrict__ xz,
                                                   const float* __restrict__ A_log,
                                                   const float* __restrict__ Dp) {
  int b = blockIdx.y;
  int d0 = blockIdx.x * 16;
  int tid = threadIdx.x;
  int s = tid & 15, dl = tid >> 4;
  int d = d0 + dl;
  float Aval = -__expf(A_log[d * 16 + s]);
  float Dval = Dp[d];
  float h = 0.f;
  __shared__ float sdel[TS][16], sxc[TS][16], sz[TS][16], sB[TS][16], sC[TS][16], sy[TS][16];
  const long base = (long)b * L_SEQ;
  for (int t0 = 0; t0 < L_SEQ; t0 += TS) {
    for (int p = tid; p < TS * 16; p += 256) {
      int tt = p >> 4, j = p & 15;
      long row = base + t0 + tt;
      sdel[tt][j] = delta[row * 512 + d0 + j];
      sxc[tt][j] = xc[row * 512 + d0 + j];
      sz[tt][j] = xz[row * 1024 + 512 + d0 + j];
      sB[tt][j] = xdb[row * 48 + 16 + j];
      sC[tt][j] = xdb[row * 48 + 32 + j];
    }
    __syncthreads();
#pragma unroll 4
    for (int tt = 0; tt < TS; ++tt) {
      float dlv = sdel[tt][dl];
      float xv = sxc[tt][dl];
      float Bv = sB[tt][s];
      float Cv = sC[tt][s];
      float dA = __expf(dlv * Aval);
      h = dA * h + (dlv * xv) * Bv;
      float yv = h * Cv;
      yv += __shfl_xor(yv, 1);
      yv += __shfl_xor(yv, 2);
      yv += __shfl_xor(yv, 4);
      yv += __shfl_xor(yv, 8);
      if (s == 0) {
        float zv = sz[tt][dl];
        float yf = (yv + xv * Dval) * (zv / (1.f + __expf(-zv)));
        sy[tt][dl] = yf;
      }
    }
    __syncthreads();
    for (int p = tid; p < TS * 16; p += 256) {
      int tt = p >> 4, j = p & 15;
      y[(base + t0 + tt) * 512 + d0 + j] = sy[tt][j];
    }
    __syncthreads();
  }
}

extern "C" void kernel_launch(void* const* d_in, const int* in_sizes, int n_in, void* d_out,
                              int out_size, void* d_ws, size_t ws_size, hipStream_t stream) {
  const float* input = (const float*)d_in[0];
  const float* in_proj_w = (const float*)d_in[1];
  const float* conv_w = (const float*)d_in[2];
  const float* conv_b = (const float*)d_in[3];
  const float* x_proj_w = (const float*)d_in[4];
  const float* dt_proj_w = (const float*)d_in[5];
  const float* dt_proj_b = (const float*)d_in[6];
  const float* A_log = (const float*)d_in[7];
  const float* Dp = (const float*)d_in[8];
  const float* out_proj_w = (const float*)d_in[9];
  const float* out_lin_w = (const float*)d_in[10];
  const float* out_lin_b = (const float*)d_in[11];

  char* ws = (char*)d_ws;
  float* buf_x = (float*)(ws);                // 16384*256 f32 (layer in/out)
  float* buf_xz = (float*)(ws + 16777216);    // 16384*1024
  float* buf_xc = (float*)(ws + 83886080);    // 16384*512
  float* buf_xdb = (float*)(ws + 117440512);  // 16384*48
  float* buf_dy = (float*)(ws + 120586240);   // 16384*512  (delta, then y in-place)

  transpose_in<<<dim3(64, 8, 8), dim3(32, 8), 0, stream>>>(input, buf_x);

  for (int i = 0; i < 2; ++i) {
    gemm_f32<0><<<dim3(16, 256), 256, 0, stream>>>(buf_x, 256, in_proj_w + (long)i * 1024 * 256,
                                                   buf_xz, 1024, 1024, 256, nullptr);
    conv_silu<<<32768, 256, 0, stream>>>(buf_xz, conv_w + i * 512 * 4, conv_b + i * 512, buf_xc);
    gemm_f32<0><<<dim3(1, 256), 256, 0, stream>>>(buf_xc, 512, x_proj_w + (long)i * 48 * 512,
                                                  buf_xdb, 48, 48, 512, nullptr);
    gemm_f32<1><<<dim3(8, 256), 256, 0, stream>>>(buf_xdb, 48, dt_proj_w + (long)i * 512 * 16,
                                                  buf_dy, 512, 512, 16, dt_proj_b + i * 512);
    scan_kernel<<<dim3(32, 8), 256, 0, stream>>>(buf_dy, buf_dy, buf_xc, buf_xdb, buf_xz,
                                                 A_log + (long)i * 512 * 16, Dp + i * 512);
    gemm_f32<0><<<dim3(4, 256), 256, 0, stream>>>(buf_dy, 512, out_proj_w + (long)i * 256 * 512,
                                                  buf_x, 256, 256, 512, nullptr);
  }
  gemm_f32<2><<<dim3(8, 256), 256, 0, stream>>>(buf_x, 256, out_lin_w, (float*)d_out, 0, 512, 256,
                                                out_lin_b);
}

// Round 2
// 1305.942 us; speedup vs baseline: 1.5582x; 1.5582x over previous
//
#include <hip/hip_runtime.h>
#include <cmath>

#define L_SEQ 2048
#define BATCH 8
#define CIN 256
#define DIN 512
#define M_ROWS (BATCH * L_SEQ)  // 16384
#define NC 16                   // scan chunks
#define LC 128                  // chunk length
#define TS 32                   // LDS tile (timesteps)

// ---------------- transpose (B,C,L) -> (B,L,C) ----------------
__global__ __launch_bounds__(256) void transpose_in(const float* __restrict__ in,
                                                    float* __restrict__ out) {
  __shared__ float tile[32][33];
  int b = blockIdx.z;
  int l0 = blockIdx.x * 32, c0 = blockIdx.y * 32;
  int tx = threadIdx.x, ty = threadIdx.y;  // 32 x 8
#pragma unroll
  for (int k = 0; k < 4; ++k)
    tile[ty + k * 8][tx] = in[(long)(b * CIN + c0 + ty + k * 8) * L_SEQ + l0 + tx];
  __syncthreads();
#pragma unroll
  for (int k = 0; k < 4; ++k)
    out[(long)(b * L_SEQ + l0 + ty + k * 8) * CIN + c0 + tx] = tile[tx][ty + k * 8];
}

// ---------------- fp32 SIMT GEMM:  C[m,n] = sum_k A[m,k] * W[n,k] ----------------
// EPI 0: plain store   EPI 1: softplus(v + bias[n])   EPI 2: relu(v+bias) + scatter to (spk,b,c,l)
template <int EPI>
__global__ __launch_bounds__(256) void gemm_f32(const float* __restrict__ A, int lda,
                                                const float* __restrict__ W,
                                                float* __restrict__ C, int ldc, int N, int K,
                                                const float* __restrict__ bias) {
  __shared__ float As[16][65];
  __shared__ float Ws[16][65];
  int tid = threadIdx.x;
  int tx = tid & 15, ty = tid >> 4;
  int m0 = blockIdx.y * 64, n0 = blockIdx.x * 64;
  float acc[4][4] = {};
  for (int k0 = 0; k0 < K; k0 += 16) {
#pragma unroll
    for (int r = 0; r < 4; ++r) {
      int p = tid + r * 256;
      int i = p >> 4, k = p & 15;
      As[k][i] = A[(long)(m0 + i) * lda + k0 + k];
      float wv = 0.f;
      if (n0 + i < N) wv = W[(long)(n0 + i) * K + k0 + k];
      Ws[k][i] = wv;
    }
    __syncthreads();
#pragma unroll
    for (int kk = 0; kk < 16; ++kk) {
      float ar[4], br[4];
#pragma unroll
      for (int i = 0; i < 4; ++i) ar[i] = As[kk][(EPI == 2 ? tx : ty) + i * 16];
#pragma unroll
      for (int j = 0; j < 4; ++j) br[j] = Ws[kk][(EPI == 2 ? ty : tx) + j * 16];
#pragma unroll
      for (int i = 0; i < 4; ++i)
#pragma unroll
        for (int j = 0; j < 4; ++j) acc[i][j] += ar[i] * br[j];
    }
    __syncthreads();
  }
#pragma unroll
  for (int i = 0; i < 4; ++i) {
#pragma unroll
    for (int j = 0; j < 4; ++j) {
      if (EPI == 2) {
        int m = m0 + tx + i * 16;
        int n = n0 + ty + j * 16;
        if (n < N) {
          float v = acc[i][j] + bias[n];
          v = v > 0.f ? v : 0.f;
          int b = m >> 11, l = m & 2047;
          int spk = n >> 8, c = n & 255;
          C[(((long)(spk * BATCH + b)) * CIN + c) * L_SEQ + l] = v;
        }
      } else {
        int m = m0 + ty + i * 16;
        int n = n0 + tx + j * 16;
        if (n < N) {
          float v = acc[i][j];
          if (EPI == 1) {
            v += bias[n];
            v = (v > 20.f) ? v : log1pf(__expf(v));
          }
          C[(long)m * ldc + n] = v;
        }
      }
    }
  }
}

// ---------------- depthwise causal conv(4) + bias + SiLU ----------------
__global__ __launch_bounds__(256) void conv_silu(const float* __restrict__ xz,
                                                 const float* __restrict__ cw,
                                                 const float* __restrict__ cb,
                                                 float* __restrict__ xc) {
  int idx = blockIdx.x * 256 + threadIdx.x;  // over M_ROWS*512
  int d = idx & 511;
  int ml = idx >> 9;
  int l = ml & 2047;
  float acc = cb[d];
  const float* w = cw + d * 4;
#pragma unroll
  for (int k = 0; k < 4; ++k) {
    int ll = l + k - 3;
    if (ll >= 0) acc += w[k] * xz[(long)(ml + k - 3) * 1024 + d];
  }
  xc[(long)ml * 512 + d] = acc / (1.f + __expf(-acc));
}

// ---------------- chunked selective scan ----------------
// h_t = dA_t h_{t-1} + dBx_t, linear in h  =>  per chunk: h_end = (prod dA) h_start + h_local
// Pass 1: per-chunk (P = prod dA, Hl = local end state with h_start=0)
// Pass 2: serial combine over NC chunks -> H0 (start state per chunk)
// Pass 3: recompute with true h_start, y = C.h, epilogue, write y (over delta, in place)
// Block: 16 d x 16 s = 256 threads; grid (DIN/16, NC, B)

__global__ __launch_bounds__(256) void scan_pass1(const float* __restrict__ delta,
                                                  const float* __restrict__ xc,
                                                  const float* __restrict__ xdb,
                                                  const float* __restrict__ A_log,
                                                  float* __restrict__ P,
                                                  float* __restrict__ Hl) {
  int b = blockIdx.z, c = blockIdx.y, d0 = blockIdx.x * 16;
  int tid = threadIdx.x;
  int s = tid & 15, dl = tid >> 4;
  int d = d0 + dl;
  float Aval = -__expf(A_log[d * 16 + s]);
  float h = 0.f, p = 1.f;
  __shared__ float sdel[TS][16], sxc[TS][16], sB[TS][16];
  const long base = (long)b * L_SEQ + (long)c * LC;
  for (int t0 = 0; t0 < LC; t0 += TS) {
    for (int q = tid; q < TS * 16; q += 256) {
      int tt = q >> 4, j = q & 15;
      long row = base + t0 + tt;
      sdel[tt][j] = delta[row * 512 + d0 + j];
      sxc[tt][j] = xc[row * 512 + d0 + j];
      sB[tt][j] = xdb[row * 48 + 16 + j];
    }
    __syncthreads();
#pragma unroll 8
    for (int tt = 0; tt < TS; ++tt) {
      float dlv = sdel[tt][dl];
      float dA = __expf(dlv * Aval);
      h = dA * h + (dlv * sxc[tt][dl]) * sB[tt][s];
      p *= dA;
    }
    __syncthreads();
  }
  long idx = (((long)b * NC + c) * 512 + d) * 16 + s;
  P[idx] = p;
  Hl[idx] = h;
}

__global__ __launch_bounds__(256) void scan_combine(const float* __restrict__ P,
                                                    const float* __restrict__ Hl,
                                                    float* __restrict__ H0) {
  int idx = blockIdx.x * 256 + threadIdx.x;  // over B*512*16 = 65536
  int b = idx >> 13;
  int ds = idx & 8191;
  float h = 0.f;
#pragma unroll
  for (int c = 0; c < NC; ++c) {
    long off = (((long)b * NC + c) << 13) + ds;
    H0[off] = h;
    h = P[off] * h + Hl[off];
  }
}

__global__ __launch_bounds__(256) void scan_pass2(const float* __restrict__ delta,
                                                  float* __restrict__ y,
                                                  const float* __restrict__ xc,
                                                  const float* __restrict__ xdb,
                                                  const float* __restrict__ xz,
                                                  const float* __restrict__ A_log,
                                                  const float* __restrict__ Dp,
                                                  const float* __restrict__ H0) {
  int b = blockIdx.z, c = blockIdx.y, d0 = blockIdx.x * 16;
  int tid = threadIdx.x;
  int s = tid & 15, dl = tid >> 4;
  int d = d0 + dl;
  float Aval = -__expf(A_log[d * 16 + s]);
  float Dval = Dp[d];
  float h = H0[(((long)b * NC + c) * 512 + d) * 16 + s];
  __shared__ float sdel[TS][16], sxc[TS][16], sz[TS][16], sB[TS][16], sC[TS][16], sy[TS][16];
  const long base = (long)b * L_SEQ + (long)c * LC;
  for (int t0 = 0; t0 < LC; t0 += TS) {
    for (int q = tid; q < TS * 16; q += 256) {
      int tt = q >> 4, j = q & 15;
      long row = base + t0 + tt;
      sdel[tt][j] = delta[row * 512 + d0 + j];
      sxc[tt][j] = xc[row * 512 + d0 + j];
      sz[tt][j] = xz[row * 1024 + 512 + d0 + j];
      sB[tt][j] = xdb[row * 48 + 16 + j];
      sC[tt][j] = xdb[row * 48 + 32 + j];
    }
    __syncthreads();
#pragma unroll 8
    for (int tt = 0; tt < TS; ++tt) {
      float dlv = sdel[tt][dl];
      float xv = sxc[tt][dl];
      float dA = __expf(dlv * Aval);
      h = dA * h + (dlv * xv) * sB[tt][s];
      float yv = h * sC[tt][s];
      yv += __shfl_xor(yv, 1);
      yv += __shfl_xor(yv, 2);
      yv += __shfl_xor(yv, 4);
      yv += __shfl_xor(yv, 8);
      if (s == 0) {
        float zv = sz[tt][dl];
        sy[tt][dl] = (yv + xv * Dval) * (zv / (1.f + __expf(-zv)));
      }
    }
    __syncthreads();
    for (int q = tid; q < TS * 16; q += 256) {
      int tt = q >> 4, j = q & 15;
      y[(base + t0 + tt) * 512 + d0 + j] = sy[tt][j];
    }
    __syncthreads();
  }
}

extern "C" void kernel_launch(void* const* d_in, const int* in_sizes, int n_in, void* d_out,
                              int out_size, void* d_ws, size_t ws_size, hipStream_t stream) {
  const float* input = (const float*)d_in[0];
  const float* in_proj_w = (const float*)d_in[1];
  const float* conv_w = (const float*)d_in[2];
  const float* conv_b = (const float*)d_in[3];
  const float* x_proj_w = (const float*)d_in[4];
  const float* dt_proj_w = (const float*)d_in[5];
  const float* dt_proj_b = (const float*)d_in[6];
  const float* A_log = (const float*)d_in[7];
  const float* Dp = (const float*)d_in[8];
  const float* out_proj_w = (const float*)d_in[9];
  const float* out_lin_w = (const float*)d_in[10];
  const float* out_lin_b = (const float*)d_in[11];

  char* ws = (char*)d_ws;
  float* buf_x = (float*)(ws);                // 16384*256 f32 (layer in/out)
  float* buf_xz = (float*)(ws + 16777216);    // 16384*1024
  float* buf_xc = (float*)(ws + 83886080);    // 16384*512
  float* buf_xdb = (float*)(ws + 117440512);  // 16384*48
  float* buf_dy = (float*)(ws + 120586240);   // 16384*512  (delta, then y in-place)
  // scan temporaries alias buf_x (dead between in_proj-read and out_proj-write):
  float* buf_P = buf_x;                  // 8*16*512*16 = 1M floats
  float* buf_Hl = buf_x + (1 << 20);     // 1M floats
  float* buf_H0 = buf_x + (2 << 20);     // 1M floats  (12 MB total < 16.7 MB region)

  transpose_in<<<dim3(64, 8, 8), dim3(32, 8), 0, stream>>>(input, buf_x);

  for (int i = 0; i < 2; ++i) {
    gemm_f32<0><<<dim3(16, 256), 256, 0, stream>>>(buf_x, 256, in_proj_w + (long)i * 1024 * 256,
                                                   buf_xz, 1024, 1024, 256, nullptr);
    conv_silu<<<32768, 256, 0, stream>>>(buf_xz, conv_w + i * 512 * 4, conv_b + i * 512, buf_xc);
    gemm_f32<0><<<dim3(1, 256), 256, 0, stream>>>(buf_xc, 512, x_proj_w + (long)i * 48 * 512,
                                                  buf_xdb, 48, 48, 512, nullptr);
    gemm_f32<1><<<dim3(8, 256), 256, 0, stream>>>(buf_xdb, 48, dt_proj_w + (long)i * 512 * 16,
                                                  buf_dy, 512, 512, 16, dt_proj_b + i * 512);
    scan_pass1<<<dim3(32, NC, 8), 256, 0, stream>>>(buf_dy, buf_xc, buf_xdb,
                                                    A_log + (long)i * 512 * 16, buf_P, buf_Hl);
    scan_combine<<<256, 256, 0, stream>>>(buf_P, buf_Hl, buf_H0);
    scan_pass2<<<dim3(32, NC, 8), 256, 0, stream>>>(buf_dy, buf_dy, buf_xc, buf_xdb, buf_xz,
                                                    A_log + (long)i * 512 * 16, Dp + i * 512,
                                                    buf_H0);
    gemm_f32<0><<<dim3(4, 256), 256, 0, stream>>>(buf_dy, 512, out_proj_w + (long)i * 256 * 512,
                                                  buf_x, 256, 256, 512, nullptr);
  }
  gemm_f32<2><<<dim3(8, 256), 256, 0, stream>>>(buf_x, 256, out_lin_w, (float*)d_out, 0, 512, 256,
                                                out_lin_b);
}

// Round 3
// 919.735 us; speedup vs baseline: 2.2125x; 1.4199x over previous
//
#include <hip/hip_runtime.h>
#include <cmath>

#define L_SEQ 2048
#define BATCH 8
#define CIN 256
#define DIN 512
#define M_ROWS (BATCH * L_SEQ)  // 16384
#define NC 16                   // scan chunks
#define LC 128                  // chunk length
#define TS 32                   // LDS tile (timesteps)

typedef __attribute__((ext_vector_type(8))) short short8;
typedef __attribute__((ext_vector_type(4))) float float4v;
typedef __attribute__((ext_vector_type(4))) unsigned short ushort4v;

__device__ inline unsigned short f2bf_rn(float x) {
  union { float f; unsigned u; } v;
  v.f = x;
  unsigned r = v.u + 0x7FFF + ((v.u >> 16) & 1);
  return (unsigned short)(r >> 16);
}
__device__ inline float bf2f(unsigned short h) {
  union { unsigned u; float f; } v;
  v.u = ((unsigned)h) << 16;
  return v.f;
}

// ---------------- transpose (B,C,L) -> (B,L,C) ----------------
__global__ __launch_bounds__(256) void transpose_in(const float* __restrict__ in,
                                                    float* __restrict__ out) {
  __shared__ float tile[32][33];
  int b = blockIdx.z;
  int l0 = blockIdx.x * 32, c0 = blockIdx.y * 32;
  int tx = threadIdx.x, ty = threadIdx.y;  // 32 x 8
#pragma unroll
  for (int k = 0; k < 4; ++k)
    tile[ty + k * 8][tx] = in[(long)(b * CIN + c0 + ty + k * 8) * L_SEQ + l0 + tx];
  __syncthreads();
#pragma unroll
  for (int k = 0; k < 4; ++k)
    out[(long)(b * L_SEQ + l0 + ty + k * 8) * CIN + c0 + tx] = tile[tx][ty + k * 8];
}

// ---------------- bf16x3 MFMA GEMM:  C[m,n] = sum_k A[m,k] * W[n,k] ----------------
// fp32 operands split in staging: x = hi + lo (bf16 each); acc += Ah*Wh + Al*Wh + Ah*Wl.
// Tiles: 128x128x32, 4 waves, each wave 64x64 as 4x4 of 16x16x32 MFMA.
// Requires M%128==0, N%128==0, K%32==0 (exact for in_proj/out_proj/out_lin).
// EPI 0: plain fp32 store.  EPI 2: relu(v+bias[n]) scattered to (spk,b,c,l) with float4.
#define LDSROW 40  // halfs per LDS row (32 + 8 pad), keeps 16B alignment
template <int EPI>
__global__ __launch_bounds__(256) void gemm_mfma(const float* __restrict__ A, int lda,
                                                 const float* __restrict__ W,
                                                 float* __restrict__ C, int ldc, int K,
                                                 const float* __restrict__ bias) {
  __shared__ unsigned short Ah[128 * LDSROW], Al[128 * LDSROW];
  __shared__ unsigned short Wh[128 * LDSROW], Wl[128 * LDSROW];
  int tid = threadIdx.x;
  int w = tid >> 6, L = tid & 63;
  int q = L >> 4, r16 = L & 15;
  int wm = (w >> 1) * 64, wn = (w & 1) * 64;
  long m0 = (long)blockIdx.y * 128, n0 = (long)blockIdx.x * 128;
  float4v acc[4][4];
#pragma unroll
  for (int i = 0; i < 4; ++i)
#pragma unroll
    for (int j = 0; j < 4; ++j) acc[i][j] = (float4v){0.f, 0.f, 0.f, 0.f};

  int lrow = tid >> 3;            // 0..31
  int lchunk = (tid & 7) * 4;     // float-chunk within the 32-wide k tile

  for (int k0 = 0; k0 < K; k0 += 32) {
#pragma unroll
    for (int p = 0; p < 4; ++p) {
      int row = lrow + p * 32;
      float4v av = *(const float4v*)&A[(m0 + row) * lda + k0 + lchunk];
      float4v wv = *(const float4v*)&W[(n0 + row) * K + k0 + lchunk];
      ushort4v ahv, alv, whv, wlv;
#pragma unroll
      for (int e = 0; e < 4; ++e) {
        unsigned short h = f2bf_rn(av[e]);
        ahv[e] = h;
        alv[e] = f2bf_rn(av[e] - bf2f(h));
        h = f2bf_rn(wv[e]);
        whv[e] = h;
        wlv[e] = f2bf_rn(wv[e] - bf2f(h));
      }
      *(ushort4v*)&Ah[row * LDSROW + lchunk] = ahv;
      *(ushort4v*)&Al[row * LDSROW + lchunk] = alv;
      *(ushort4v*)&Wh[row * LDSROW + lchunk] = whv;
      *(ushort4v*)&Wl[row * LDSROW + lchunk] = wlv;
    }
    __syncthreads();
    short8 ah[4], al[4], bh[4], bl[4];
#pragma unroll
    for (int i = 0; i < 4; ++i) {
      int mr = wm + i * 16 + r16;
      ah[i] = *(const short8*)&Ah[mr * LDSROW + q * 8];
      al[i] = *(const short8*)&Al[mr * LDSROW + q * 8];
    }
#pragma unroll
    for (int j = 0; j < 4; ++j) {
      int nr = wn + j * 16 + r16;
      bh[j] = *(const short8*)&Wh[nr * LDSROW + q * 8];
      bl[j] = *(const short8*)&Wl[nr * LDSROW + q * 8];
    }
#pragma unroll
    for (int i = 0; i < 4; ++i)
#pragma unroll
      for (int j = 0; j < 4; ++j) {
        acc[i][j] = __builtin_amdgcn_mfma_f32_16x16x32_bf16(ah[i], bh[j], acc[i][j], 0, 0, 0);
        acc[i][j] = __builtin_amdgcn_mfma_f32_16x16x32_bf16(al[i], bh[j], acc[i][j], 0, 0, 0);
        acc[i][j] = __builtin_amdgcn_mfma_f32_16x16x32_bf16(ah[i], bl[j], acc[i][j], 0, 0, 0);
      }
    __syncthreads();
  }

  // Epilogue. D layout (16x16x32): row = q*4 + r, col = r16   [m89/m91 verified]
#pragma unroll
  for (int i = 0; i < 4; ++i) {
    int m = (int)m0 + wm + i * 16 + q * 4;
#pragma unroll
    for (int j = 0; j < 4; ++j) {
      int n = (int)n0 + wn + j * 16 + r16;
      if (EPI == 0) {
#pragma unroll
        for (int r = 0; r < 4; ++r) C[(long)(m + r) * ldc + n] = acc[i][j][r];
      } else {  // EPI == 2
        float vb = bias[n];
        int spk = n >> 8, c = n & 255;
        int b = m >> 11, l = m & 2047;
        float4v v;
#pragma unroll
        for (int r = 0; r < 4; ++r) {
          float t = acc[i][j][r] + vb;
          v[r] = t > 0.f ? t : 0.f;
        }
        *(float4v*)&C[(((long)(spk * BATCH + b)) * CIN + c) * L_SEQ + l] = v;
      }
    }
  }
}

// ---------------- fp32 SIMT GEMM (small shapes: x_proj N=48, dt_proj K=16) ----------------
// EPI 0: plain store   EPI 1: softplus(v + bias[n])
template <int EPI>
__global__ __launch_bounds__(256) void gemm_f32(const float* __restrict__ A, int lda,
                                                const float* __restrict__ W,
                                                float* __restrict__ C, int ldc, int N, int K,
                                                const float* __restrict__ bias) {
  __shared__ float As[16][65];
  __shared__ float Ws[16][65];
  int tid = threadIdx.x;
  int tx = tid & 15, ty = tid >> 4;
  int m0 = blockIdx.y * 64, n0 = blockIdx.x * 64;
  float acc[4][4] = {};
  for (int k0 = 0; k0 < K; k0 += 16) {
#pragma unroll
    for (int r = 0; r < 4; ++r) {
      int p = tid + r * 256;
      int i = p >> 4, k = p & 15;
      As[k][i] = A[(long)(m0 + i) * lda + k0 + k];
      float wv = 0.f;
      if (n0 + i < N) wv = W[(long)(n0 + i) * K + k0 + k];
      Ws[k][i] = wv;
    }
    __syncthreads();
#pragma unroll
    for (int kk = 0; kk < 16; ++kk) {
      float ar[4], br[4];
#pragma unroll
      for (int i = 0; i < 4; ++i) ar[i] = As[kk][ty + i * 16];
#pragma unroll
      for (int j = 0; j < 4; ++j) br[j] = Ws[kk][tx + j * 16];
#pragma unroll
      for (int i = 0; i < 4; ++i)
#pragma unroll
        for (int j = 0; j < 4; ++j) acc[i][j] += ar[i] * br[j];
    }
    __syncthreads();
  }
#pragma unroll
  for (int i = 0; i < 4; ++i) {
#pragma unroll
    for (int j = 0; j < 4; ++j) {
      int m = m0 + ty + i * 16;
      int n = n0 + tx + j * 16;
      if (n < N) {
        float v = acc[i][j];
        if (EPI == 1) {
          v += bias[n];
          v = (v > 20.f) ? v : log1pf(__expf(v));
        }
        C[(long)m * ldc + n] = v;
      }
    }
  }
}

// ---------------- depthwise causal conv(4) + bias + SiLU ----------------
__global__ __launch_bounds__(256) void conv_silu(const float* __restrict__ xz,
                                                 const float* __restrict__ cw,
                                                 const float* __restrict__ cb,
                                                 float* __restrict__ xc) {
  int idx = blockIdx.x * 256 + threadIdx.x;  // over M_ROWS*512
  int d = idx & 511;
  int ml = idx >> 9;
  int l = ml & 2047;
  float acc = cb[d];
  const float* w = cw + d * 4;
#pragma unroll
  for (int k = 0; k < 4; ++k) {
    int ll = l + k - 3;
    if (ll >= 0) acc += w[k] * xz[(long)(ml + k - 3) * 1024 + d];
  }
  xc[(long)ml * 512 + d] = acc / (1.f + __expf(-acc));
}

// ---------------- chunked selective scan ----------------
__global__ __launch_bounds__(256) void scan_pass1(const float* __restrict__ delta,
                                                  const float* __restrict__ xc,
                                                  const float* __restrict__ xdb,
                                                  const float* __restrict__ A_log,
                                                  float* __restrict__ P,
                                                  float* __restrict__ Hl) {
  int b = blockIdx.z, c = blockIdx.y, d0 = blockIdx.x * 16;
  int tid = threadIdx.x;
  int s = tid & 15, dl = tid >> 4;
  int d = d0 + dl;
  float Aval = -__expf(A_log[d * 16 + s]);
  float h = 0.f, p = 1.f;
  __shared__ float sdel[TS][16], sxc[TS][16], sB[TS][16];
  const long base = (long)b * L_SEQ + (long)c * LC;
  for (int t0 = 0; t0 < LC; t0 += TS) {
    for (int q = tid; q < TS * 16; q += 256) {
      int tt = q >> 4, j = q & 15;
      long row = base + t0 + tt;
      sdel[tt][j] = delta[row * 512 + d0 + j];
      sxc[tt][j] = xc[row * 512 + d0 + j];
      sB[tt][j] = xdb[row * 48 + 16 + j];
    }
    __syncthreads();
#pragma unroll 8
    for (int tt = 0; tt < TS; ++tt) {
      float dlv = sdel[tt][dl];
      float dA = __expf(dlv * Aval);
      h = dA * h + (dlv * sxc[tt][dl]) * sB[tt][s];
      p *= dA;
    }
    __syncthreads();
  }
  long idx = (((long)b * NC + c) * 512 + d) * 16 + s;
  P[idx] = p;
  Hl[idx] = h;
}

__global__ __launch_bounds__(256) void scan_combine(const float* __restrict__ P,
                                                    const float* __restrict__ Hl,
                                                    float* __restrict__ H0) {
  int idx = blockIdx.x * 256 + threadIdx.x;  // over B*512*16 = 65536
  int b = idx >> 13;
  int ds = idx & 8191;
  float h = 0.f;
#pragma unroll
  for (int c = 0; c < NC; ++c) {
    long off = (((long)b * NC + c) << 13) + ds;
    H0[off] = h;
    h = P[off] * h + Hl[off];
  }
}

__global__ __launch_bounds__(256) void scan_pass2(const float* __restrict__ delta,
                                                  float* __restrict__ y,
                                                  const float* __restrict__ xc,
                                                  const float* __restrict__ xdb,
                                                  const float* __restrict__ xz,
                                                  const float* __restrict__ A_log,
                                                  const float* __restrict__ Dp,
                                                  const float* __restrict__ H0) {
  int b = blockIdx.z, c = blockIdx.y, d0 = blockIdx.x * 16;
  int tid = threadIdx.x;
  int s = tid & 15, dl = tid >> 4;
  int d = d0 + dl;
  float Aval = -__expf(A_log[d * 16 + s]);
  float Dval = Dp[d];
  float h = H0[(((long)b * NC + c) * 512 + d) * 16 + s];
  __shared__ float sdel[TS][16], sxc[TS][16], sz[TS][16], sB[TS][16], sC[TS][16], sy[TS][16];
  const long base = (long)b * L_SEQ + (long)c * LC;
  for (int t0 = 0; t0 < LC; t0 += TS) {
    for (int q = tid; q < TS * 16; q += 256) {
      int tt = q >> 4, j = q & 15;
      long row = base + t0 + tt;
      sdel[tt][j] = delta[row * 512 + d0 + j];
      sxc[tt][j] = xc[row * 512 + d0 + j];
      sz[tt][j] = xz[row * 1024 + 512 + d0 + j];
      sB[tt][j] = xdb[row * 48 + 16 + j];
      sC[tt][j] = xdb[row * 48 + 32 + j];
    }
    __syncthreads();
#pragma unroll 8
    for (int tt = 0; tt < TS; ++tt) {
      float dlv = sdel[tt][dl];
      float xv = sxc[tt][dl];
      float dA = __expf(dlv * Aval);
      h = dA * h + (dlv * xv) * sB[tt][s];
      float yv = h * sC[tt][s];
      yv += __shfl_xor(yv, 1);
      yv += __shfl_xor(yv, 2);
      yv += __shfl_xor(yv, 4);
      yv += __shfl_xor(yv, 8);
      if (s == 0) {
        float zv = sz[tt][dl];
        sy[tt][dl] = (yv + xv * Dval) * (zv / (1.f + __expf(-zv)));
      }
    }
    __syncthreads();
    for (int q = tid; q < TS * 16; q += 256) {
      int tt = q >> 4, j = q & 15;
      y[(base + t0 + tt) * 512 + d0 + j] = sy[tt][j];
    }
    __syncthreads();
  }
}

extern "C" void kernel_launch(void* const* d_in, const int* in_sizes, int n_in, void* d_out,
                              int out_size, void* d_ws, size_t ws_size, hipStream_t stream) {
  const float* input = (const float*)d_in[0];
  const float* in_proj_w = (const float*)d_in[1];
  const float* conv_w = (const float*)d_in[2];
  const float* conv_b = (const float*)d_in[3];
  const float* x_proj_w = (const float*)d_in[4];
  const float* dt_proj_w = (const float*)d_in[5];
  const float* dt_proj_b = (const float*)d_in[6];
  const float* A_log = (const float*)d_in[7];
  const float* Dp = (const float*)d_in[8];
  const float* out_proj_w = (const float*)d_in[9];
  const float* out_lin_w = (const float*)d_in[10];
  const float* out_lin_b = (const float*)d_in[11];

  char* ws = (char*)d_ws;
  float* buf_x = (float*)(ws);                // 16384*256 f32 (layer in/out)
  float* buf_xz = (float*)(ws + 16777216);    // 16384*1024
  float* buf_xc = (float*)(ws + 83886080);    // 16384*512
  float* buf_xdb = (float*)(ws + 117440512);  // 16384*48
  float* buf_dy = (float*)(ws + 120586240);   // 16384*512  (delta, then y in-place)
  // scan temporaries alias buf_x (dead between in_proj-read and out_proj-write):
  float* buf_P = buf_x;               // 1M floats
  float* buf_Hl = buf_x + (1 << 20);  // 1M floats
  float* buf_H0 = buf_x + (2 << 20);  // 1M floats

  transpose_in<<<dim3(64, 8, 8), dim3(32, 8), 0, stream>>>(input, buf_x);

  for (int i = 0; i < 2; ++i) {
    gemm_mfma<0><<<dim3(8, 128), 256, 0, stream>>>(buf_x, 256, in_proj_w + (long)i * 1024 * 256,
                                                   buf_xz, 1024, 256, nullptr);
    conv_silu<<<32768, 256, 0, stream>>>(buf_xz, conv_w + i * 512 * 4, conv_b + i * 512, buf_xc);
    gemm_f32<0><<<dim3(1, 256), 256, 0, stream>>>(buf_xc, 512, x_proj_w + (long)i * 48 * 512,
                                                  buf_xdb, 48, 48, 512, nullptr);
    gemm_f32<1><<<dim3(8, 256), 256, 0, stream>>>(buf_xdb, 48, dt_proj_w + (long)i * 512 * 16,
                                                  buf_dy, 512, 512, 16, dt_proj_b + i * 512);
    scan_pass1<<<dim3(32, NC, 8), 256, 0, stream>>>(buf_dy, buf_xc, buf_xdb,
                                                    A_log + (long)i * 512 * 16, buf_P, buf_Hl);
    scan_combine<<<256, 256, 0, stream>>>(buf_P, buf_Hl, buf_H0);
    scan_pass2<<<dim3(32, NC, 8), 256, 0, stream>>>(buf_dy, buf_dy, buf_xc, buf_xdb, buf_xz,
                                                    A_log + (long)i * 512 * 16, Dp + i * 512,
                                                    buf_H0);
    gemm_mfma<0><<<dim3(2, 128), 256, 0, stream>>>(buf_dy, 512, out_proj_w + (long)i * 256 * 512,
                                                   buf_x, 256, 512, nullptr);
  }
  gemm_mfma<2><<<dim3(4, 128), 256, 0, stream>>>(buf_x, 256, out_lin_w, (float*)d_out, 0, 256,
                                                 out_lin_b);
}

// Round 4
// 713.016 us; speedup vs baseline: 2.8539x; 1.2899x over previous
//
#include <hip/hip_runtime.h>
#include <cmath>

#define L_SEQ 2048
#define BATCH 8
#define CIN 256
#define DIN 512
#define M_ROWS (BATCH * L_SEQ)  // 16384
#define NC 64                   // scan chunks
#define LC 32                   // chunk length

typedef __attribute__((ext_vector_type(8))) short short8;
typedef __attribute__((ext_vector_type(4))) float float4v;
typedef __attribute__((ext_vector_type(4))) unsigned short ushort4v;

__device__ inline unsigned short f2bf_rn(float x) {
  union { float f; unsigned u; } v;
  v.f = x;
  unsigned r = v.u + 0x7FFF + ((v.u >> 16) & 1);
  return (unsigned short)(r >> 16);
}
__device__ inline float bf2f(unsigned short h) {
  union { unsigned u; float f; } v;
  v.u = ((unsigned)h) << 16;
  return v.f;
}

// ---------------- transpose (B,C,L) -> (B,L,C) ----------------
__global__ __launch_bounds__(256) void transpose_in(const float* __restrict__ in,
                                                    float* __restrict__ out) {
  __shared__ float tile[32][33];
  int b = blockIdx.z;
  int l0 = blockIdx.x * 32, c0 = blockIdx.y * 32;
  int tx = threadIdx.x, ty = threadIdx.y;  // 32 x 8
#pragma unroll
  for (int k = 0; k < 4; ++k)
    tile[ty + k * 8][tx] = in[(long)(b * CIN + c0 + ty + k * 8) * L_SEQ + l0 + tx];
  __syncthreads();
#pragma unroll
  for (int k = 0; k < 4; ++k)
    out[(long)(b * L_SEQ + l0 + ty + k * 8) * CIN + c0 + tx] = tile[tx][ty + k * 8];
}

// ---------------- bf16x3 MFMA GEMM:  C[m,n] = sum_k A[m,k] * W[n,k] ----------------
// EPI 0: plain fp32 store.  EPI 2: relu(v+bias) scatter to (spk,b,c,l).  EPI 3: split store
// (n<512 -> C, else C2 at n-512; both row stride 512).
#define LDSROW 40
template <int EPI>
__global__ __launch_bounds__(256) void gemm_mfma(const float* __restrict__ A, int lda,
                                                 const float* __restrict__ W,
                                                 float* __restrict__ C, float* __restrict__ C2,
                                                 int ldc, int K, const float* __restrict__ bias) {
  __shared__ unsigned short Ah[128 * LDSROW], Al[128 * LDSROW];
  __shared__ unsigned short Wh[128 * LDSROW], Wl[128 * LDSROW];
  int tid = threadIdx.x;
  int w = tid >> 6, L = tid & 63;
  int q = L >> 4, r16 = L & 15;
  int wm = (w >> 1) * 64, wn = (w & 1) * 64;
  long m0 = (long)blockIdx.y * 128, n0 = (long)blockIdx.x * 128;
  float4v acc[4][4];
#pragma unroll
  for (int i = 0; i < 4; ++i)
#pragma unroll
    for (int j = 0; j < 4; ++j) acc[i][j] = (float4v){0.f, 0.f, 0.f, 0.f};

  int lrow = tid >> 3;
  int lchunk = (tid & 7) * 4;

  for (int k0 = 0; k0 < K; k0 += 32) {
#pragma unroll
    for (int p = 0; p < 4; ++p) {
      int row = lrow + p * 32;
      float4v av = *(const float4v*)&A[(m0 + row) * lda + k0 + lchunk];
      float4v wv = *(const float4v*)&W[(n0 + row) * K + k0 + lchunk];
      ushort4v ahv, alv, whv, wlv;
#pragma unroll
      for (int e = 0; e < 4; ++e) {
        unsigned short h = f2bf_rn(av[e]);
        ahv[e] = h;
        alv[e] = f2bf_rn(av[e] - bf2f(h));
        h = f2bf_rn(wv[e]);
        whv[e] = h;
        wlv[e] = f2bf_rn(wv[e] - bf2f(h));
      }
      *(ushort4v*)&Ah[row * LDSROW + lchunk] = ahv;
      *(ushort4v*)&Al[row * LDSROW + lchunk] = alv;
      *(ushort4v*)&Wh[row * LDSROW + lchunk] = whv;
      *(ushort4v*)&Wl[row * LDSROW + lchunk] = wlv;
    }
    __syncthreads();
    short8 ah[4], al[4], bh[4], bl[4];
#pragma unroll
    for (int i = 0; i < 4; ++i) {
      int mr = wm + i * 16 + r16;
      ah[i] = *(const short8*)&Ah[mr * LDSROW + q * 8];
      al[i] = *(const short8*)&Al[mr * LDSROW + q * 8];
    }
#pragma unroll
    for (int j = 0; j < 4; ++j) {
      int nr = wn + j * 16 + r16;
      bh[j] = *(const short8*)&Wh[nr * LDSROW + q * 8];
      bl[j] = *(const short8*)&Wl[nr * LDSROW + q * 8];
    }
#pragma unroll
    for (int i = 0; i < 4; ++i)
#pragma unroll
      for (int j = 0; j < 4; ++j) {
        acc[i][j] = __builtin_amdgcn_mfma_f32_16x16x32_bf16(ah[i], bh[j], acc[i][j], 0, 0, 0);
        acc[i][j] = __builtin_amdgcn_mfma_f32_16x16x32_bf16(al[i], bh[j], acc[i][j], 0, 0, 0);
        acc[i][j] = __builtin_amdgcn_mfma_f32_16x16x32_bf16(ah[i], bl[j], acc[i][j], 0, 0, 0);
      }
    __syncthreads();
  }

  // D layout (16x16x32): row = q*4 + r, col = r16
#pragma unroll
  for (int i = 0; i < 4; ++i) {
    int m = (int)m0 + wm + i * 16 + q * 4;
#pragma unroll
    for (int j = 0; j < 4; ++j) {
      int n = (int)n0 + wn + j * 16 + r16;
      if (EPI == 0) {
#pragma unroll
        for (int r = 0; r < 4; ++r) C[(long)(m + r) * ldc + n] = acc[i][j][r];
      } else if (EPI == 3) {
        float* dst = (n < 512) ? C : C2;
        int nn = n & 511;
#pragma unroll
        for (int r = 0; r < 4; ++r) dst[(long)(m + r) * 512 + nn] = acc[i][j][r];
      } else {  // EPI == 2
        float vb = bias[n];
        int spk = n >> 8, c = n & 255;
        int b = m >> 11, l = m & 2047;
        float4v v;
#pragma unroll
        for (int r = 0; r < 4; ++r) {
          float t = acc[i][j][r] + vb;
          v[r] = t > 0.f ? t : 0.f;
        }
        *(float4v*)&C[(((long)(spk * BATCH + b)) * CIN + c) * L_SEQ + l] = v;
      }
    }
  }
}

// ---------------- fp32 SIMT GEMM (small shapes: x_proj N=48, dt_proj K=16) ----------------
template <int EPI>
__global__ __launch_bounds__(256) void gemm_f32(const float* __restrict__ A, int lda,
                                                const float* __restrict__ W,
                                                float* __restrict__ C, int ldc, int N, int K,
                                                const float* __restrict__ bias) {
  __shared__ float As[16][65];
  __shared__ float Ws[16][65];
  int tid = threadIdx.x;
  int tx = tid & 15, ty = tid >> 4;
  int m0 = blockIdx.y * 64, n0 = blockIdx.x * 64;
  float acc[4][4] = {};
  for (int k0 = 0; k0 < K; k0 += 16) {
#pragma unroll
    for (int r = 0; r < 4; ++r) {
      int p = tid + r * 256;
      int i = p >> 4, k = p & 15;
      As[k][i] = A[(long)(m0 + i) * lda + k0 + k];
      float wv = 0.f;
      if (n0 + i < N) wv = W[(long)(n0 + i) * K + k0 + k];
      Ws[k][i] = wv;
    }
    __syncthreads();
#pragma unroll
    for (int kk = 0; kk < 16; ++kk) {
      float ar[4], br[4];
#pragma unroll
      for (int i = 0; i < 4; ++i) ar[i] = As[kk][ty + i * 16];
#pragma unroll
      for (int j = 0; j < 4; ++j) br[j] = Ws[kk][tx + j * 16];
#pragma unroll
      for (int i = 0; i < 4; ++i)
#pragma unroll
        for (int j = 0; j < 4; ++j) acc[i][j] += ar[i] * br[j];
    }
    __syncthreads();
  }
#pragma unroll
  for (int i = 0; i < 4; ++i) {
#pragma unroll
    for (int j = 0; j < 4; ++j) {
      int m = m0 + ty + i * 16;
      int n = n0 + tx + j * 16;
      if (n < N) {
        float v = acc[i][j];
        if (EPI == 1) {
          v += bias[n];
          v = (v > 20.f) ? v : log1pf(__expf(v));
        }
        C[(long)m * ldc + n] = v;
      }
    }
  }
}

// ---------------- depthwise causal conv(4) + bias + SiLU (reads xr, stride 512) ----------------
__global__ __launch_bounds__(256) void conv_silu(const float* __restrict__ xr,
                                                 const float* __restrict__ cw,
                                                 const float* __restrict__ cb,
                                                 float* __restrict__ xc) {
  int idx = blockIdx.x * 256 + threadIdx.x;
  int d = idx & 511;
  int ml = idx >> 9;
  int l = ml & 2047;
  float acc = cb[d];
  const float* w = cw + d * 4;
#pragma unroll
  for (int k = 0; k < 4; ++k) {
    int ll = l + k - 3;
    if (ll >= 0) acc += w[k] * xr[(long)(ml + k - 3) * 512 + d];
  }
  xc[(long)ml * 512 + d] = acc / (1.f + __expf(-acc));
}

// ---------------- chunked selective scan: thread per (b,d), 16 states in registers ------------
__global__ __launch_bounds__(256) void scan_pass1(const float* __restrict__ delta,
                                                  const float* __restrict__ xc,
                                                  const float* __restrict__ xdb,
                                                  const float* __restrict__ A_log,
                                                  float* __restrict__ P,
                                                  float* __restrict__ Hl) {
  int b = blockIdx.z, c = blockIdx.y;
  int tid = threadIdx.x;
  int d = blockIdx.x * 256 + tid;
  __shared__ float sB[LC][16];
  const long base = (long)b * L_SEQ + (long)c * LC;
  for (int qq = tid; qq < LC * 16; qq += 256) {
    int tt = qq >> 4, j = qq & 15;
    sB[tt][j] = xdb[(base + tt) * 48 + 16 + j];
  }
  float Aval[16];
  {
    float4v a[4];
#pragma unroll
    for (int g = 0; g < 4; ++g) a[g] = *(const float4v*)&A_log[d * 16 + g * 4];
#pragma unroll
    for (int s = 0; s < 16; ++s) Aval[s] = -__expf(a[s >> 2][s & 3]);
  }
  __syncthreads();
  float h[16];
#pragma unroll
  for (int s = 0; s < 16; ++s) h[s] = 0.f;
  float sd = 0.f;
#pragma unroll 4
  for (int t = 0; t < LC; ++t) {
    float dlv = delta[(base + t) * 512 + d];
    float xv = xc[(base + t) * 512 + d];
    float w = dlv * xv;
    sd += dlv;
    float4v Bv[4];
#pragma unroll
    for (int g = 0; g < 4; ++g) Bv[g] = *(const float4v*)&sB[t][g * 4];
#pragma unroll
    for (int s = 0; s < 16; ++s) {
      float dA = __expf(dlv * Aval[s]);
      h[s] = dA * h[s] + w * Bv[s >> 2][s & 3];
    }
  }
  long idx = (((long)b * NC + c) * 512 + d) * 16;
#pragma unroll
  for (int g = 0; g < 4; ++g) {
    float4v pv, hv;
#pragma unroll
    for (int e = 0; e < 4; ++e) {
      pv[e] = __expf(Aval[g * 4 + e] * sd);
      hv[e] = h[g * 4 + e];
    }
    *(float4v*)&P[idx + g * 4] = pv;
    *(float4v*)&Hl[idx + g * 4] = hv;
  }
}

__global__ __launch_bounds__(256) void scan_combine(const float* __restrict__ P,
                                                    const float* __restrict__ Hl,
                                                    float* __restrict__ H0) {
  int idx = blockIdx.x * 256 + threadIdx.x;  // over B*512*16 = 65536
  int b = idx >> 13;
  int ds = idx & 8191;
  float h = 0.f;
#pragma unroll 8
  for (int c = 0; c < NC; ++c) {
    long off = (((long)b * NC + c) << 13) + ds;
    H0[off] = h;
    h = P[off] * h + Hl[off];
  }
}

__global__ __launch_bounds__(256) void scan_pass2(const float* __restrict__ delta,
                                                  float* __restrict__ y,
                                                  const float* __restrict__ xc,
                                                  const float* __restrict__ xdb,
                                                  const float* __restrict__ z,
                                                  const float* __restrict__ A_log,
                                                  const float* __restrict__ Dp,
                                                  const float* __restrict__ H0) {
  int b = blockIdx.z, c = blockIdx.y;
  int tid = threadIdx.x;
  int d = blockIdx.x * 256 + tid;
  __shared__ float sB[LC][16], sC[LC][16];
  const long base = (long)b * L_SEQ + (long)c * LC;
  for (int qq = tid; qq < LC * 16; qq += 256) {
    int tt = qq >> 4, j = qq & 15;
    sB[tt][j] = xdb[(base + tt) * 48 + 16 + j];
    sC[tt][j] = xdb[(base + tt) * 48 + 32 + j];
  }
  float Aval[16];
  {
    float4v a[4];
#pragma unroll
    for (int g = 0; g < 4; ++g) a[g] = *(const float4v*)&A_log[d * 16 + g * 4];
#pragma unroll
    for (int s = 0; s < 16; ++s) Aval[s] = -__expf(a[s >> 2][s & 3]);
  }
  float Dval = Dp[d];
  float h[16];
  {
    long hidx = (((long)b * NC + c) * 512 + d) * 16;
#pragma unroll
    for (int g = 0; g < 4; ++g) {
      float4v hv = *(const float4v*)&H0[hidx + g * 4];
#pragma unroll
      for (int e = 0; e < 4; ++e) h[g * 4 + e] = hv[e];
    }
  }
  __syncthreads();
#pragma unroll 4
  for (int t = 0; t < LC; ++t) {
    float dlv = delta[(base + t) * 512 + d];
    float xv = xc[(base + t) * 512 + d];
    float zv = z[(base + t) * 512 + d];
    float w = dlv * xv;
    float4v Bv[4], Cv[4];
#pragma unroll
    for (int g = 0; g < 4; ++g) {
      Bv[g] = *(const float4v*)&sB[t][g * 4];
      Cv[g] = *(const float4v*)&sC[t][g * 4];
    }
    float ya = 0.f, yb = 0.f, yc2 = 0.f, yd = 0.f;
#pragma unroll
    for (int s = 0; s < 4; ++s) {
      float dA = __expf(dlv * Aval[s]);
      h[s] = dA * h[s] + w * Bv[0][s];
      ya += h[s] * Cv[0][s];
    }
#pragma unroll
    for (int s = 4; s < 8; ++s) {
      float dA = __expf(dlv * Aval[s]);
      h[s] = dA * h[s] + w * Bv[1][s - 4];
      yb += h[s] * Cv[1][s - 4];
    }
#pragma unroll
    for (int s = 8; s < 12; ++s) {
      float dA = __expf(dlv * Aval[s]);
      h[s] = dA * h[s] + w * Bv[2][s - 8];
      yc2 += h[s] * Cv[2][s - 8];
    }
#pragma unroll
    for (int s = 12; s < 16; ++s) {
      float dA = __expf(dlv * Aval[s]);
      h[s] = dA * h[s] + w * Bv[3][s - 12];
      yd += h[s] * Cv[3][s - 12];
    }
    float yv = (ya + yb) + (yc2 + yd);
    float yf = (yv + xv * Dval) * (zv / (1.f + __expf(-zv)));
    y[(base + t) * 512 + d] = yf;
  }
}

extern "C" void kernel_launch(void* const* d_in, const int* in_sizes, int n_in, void* d_out,
                              int out_size, void* d_ws, size_t ws_size, hipStream_t stream) {
  const float* input = (const float*)d_in[0];
  const float* in_proj_w = (const float*)d_in[1];
  const float* conv_w = (const float*)d_in[2];
  const float* conv_b = (const float*)d_in[3];
  const float* x_proj_w = (const float*)d_in[4];
  const float* dt_proj_w = (const float*)d_in[5];
  const float* dt_proj_b = (const float*)d_in[6];
  const float* A_log = (const float*)d_in[7];
  const float* Dp = (const float*)d_in[8];
  const float* out_proj_w = (const float*)d_in[9];
  const float* out_lin_w = (const float*)d_in[10];
  const float* out_lin_b = (const float*)d_in[11];

  char* ws = (char*)d_ws;
  float* buf_x = (float*)(ws);                // 16 MB: layer in/out
  float* buf_xr = (float*)(ws + 16777216);    // 32 MB: xr half of in_proj
  float* buf_z = (float*)(ws + 50331648);     // 32 MB: z half
  float* buf_xc = (float*)(ws + 83886080);    // 32 MB: conv+silu out
  float* buf_xdb = (float*)(ws + 117440512);  // 3 MB: x_proj out
  float* buf_dy = (float*)(ws + 120586240);   // 32 MB: delta, then y in-place
  // scan temps alias dead regions: xr is dead after conv; buf_x dead between in_proj/out_proj
  float* buf_P = buf_xr;                 // 16 MB
  float* buf_Hl = buf_xr + (4 << 20);    // 16 MB
  float* buf_H0 = buf_x;                 // 16 MB

  transpose_in<<<dim3(64, 8, 8), dim3(32, 8), 0, stream>>>(input, buf_x);

  for (int i = 0; i < 2; ++i) {
    gemm_mfma<3><<<dim3(8, 128), 256, 0, stream>>>(buf_x, 256, in_proj_w + (long)i * 1024 * 256,
                                                   buf_xr, buf_z, 512, 256, nullptr);
    conv_silu<<<32768, 256, 0, stream>>>(buf_xr, conv_w + i * 512 * 4, conv_b + i * 512, buf_xc);
    gemm_f32<0><<<dim3(1, 256), 256, 0, stream>>>(buf_xc, 512, x_proj_w + (long)i * 48 * 512,
                                                  buf_xdb, 48, 48, 512, nullptr);
    gemm_f32<1><<<dim3(8, 256), 256, 0, stream>>>(buf_xdb, 48, dt_proj_w + (long)i * 512 * 16,
                                                  buf_dy, 512, 512, 16, dt_proj_b + i * 512);
    scan_pass1<<<dim3(2, NC, 8), 256, 0, stream>>>(buf_dy, buf_xc, buf_xdb,
                                                   A_log + (long)i * 512 * 16, buf_P, buf_Hl);
    scan_combine<<<256, 256, 0, stream>>>(buf_P, buf_Hl, buf_H0);
    scan_pass2<<<dim3(2, NC, 8), 256, 0, stream>>>(buf_dy, buf_dy, buf_xc, buf_xdb, buf_z,
                                                   A_log + (long)i * 512 * 16, Dp + i * 512,
                                                   buf_H0);
    gemm_mfma<0><<<dim3(2, 128), 256, 0, stream>>>(buf_dy, 512, out_proj_w + (long)i * 256 * 512,
                                                   buf_x, nullptr, 256, 512, nullptr);
  }
  gemm_mfma<2><<<dim3(4, 128), 256, 0, stream>>>(buf_x, 256, out_lin_w, (float*)d_out, nullptr, 0,
                                                 256, out_lin_b);
}

// Round 5
// 681.031 us; speedup vs baseline: 2.9880x; 1.0470x over previous
//
#include <hip/hip_runtime.h>
#include <cmath>

#define L_SEQ 2048
#define BATCH 8
#define CIN 256
#define DIN 512
#define M_ROWS (BATCH * L_SEQ)  // 16384
#define NC 64                   // scan chunks
#define LC 32                   // chunk length

typedef __attribute__((ext_vector_type(8))) short short8;
typedef __attribute__((ext_vector_type(4))) float float4v;
typedef __attribute__((ext_vector_type(4))) unsigned short ushort4v;

__device__ inline unsigned short f2bf_rn(float x) {
  union { float f; unsigned u; } v;
  v.f = x;
  unsigned r = v.u + 0x7FFF + ((v.u >> 16) & 1);
  return (unsigned short)(r >> 16);
}
__device__ inline float bf2f(unsigned short h) {
  union { unsigned u; float f; } v;
  v.u = ((unsigned)h) << 16;
  return v.f;
}

// ---------------- transpose (B,C,L) -> (B,L,C) ----------------
__global__ __launch_bounds__(256) void transpose_in(const float* __restrict__ in,
                                                    float* __restrict__ out) {
  __shared__ float tile[32][33];
  int b = blockIdx.z;
  int l0 = blockIdx.x * 32, c0 = blockIdx.y * 32;
  int tx = threadIdx.x, ty = threadIdx.y;  // 32 x 8
#pragma unroll
  for (int k = 0; k < 4; ++k)
    tile[ty + k * 8][tx] = in[(long)(b * CIN + c0 + ty + k * 8) * L_SEQ + l0 + tx];
  __syncthreads();
#pragma unroll
  for (int k = 0; k < 4; ++k)
    out[(long)(b * L_SEQ + l0 + ty + k * 8) * CIN + c0 + tx] = tile[tx][ty + k * 8];
}

// ---------------- weight-fusion precompute ----------------
// Wd (640 x 512): rows 0..511 = dt_proj_w (512x16) @ x_proj_w[0:16] (16x512)
//                 rows 512..543 = x_proj_w[16:48] (B,C rows); rows 544..639 = 0
__global__ __launch_bounds__(256) void build_wd(const float* __restrict__ xpw,
                                                const float* __restrict__ dtw,
                                                float* __restrict__ Wd) {
  int k = blockIdx.x * 256 + threadIdx.x;  // 0..511
  int n = blockIdx.y;                      // 0..639
  float v;
  if (n < 512) {
    v = 0.f;
#pragma unroll
    for (int r = 0; r < 16; ++r) v += dtw[n * 16 + r] * xpw[r * 512 + k];
  } else if (n < 544) {
    v = xpw[(16 + n - 512) * 512 + k];
  } else {
    v = 0.f;
  }
  Wd[(long)n * 512 + k] = v;
}

// W_comb (512 x 512): out_lin_w (512x256) @ out_proj_w[layer1] (256x512)
__global__ __launch_bounds__(256) void build_wcomb(const float* __restrict__ olw,
                                                   const float* __restrict__ opw,
                                                   float* __restrict__ Wc) {
  int d = blockIdx.x * 256 + threadIdx.x;  // 0..511
  int o = blockIdx.y;                      // 0..511
  float v = 0.f;
#pragma unroll 4
  for (int c = 0; c < 256; ++c) v += olw[o * 256 + c] * opw[(long)c * 512 + d];
  Wc[(long)o * 512 + d] = v;
}

// ---------------- bf16x3 MFMA GEMM:  C[m,n] = sum_k A[m,k] * W[n,k] ----------------
// EPI 0: plain fp32 store (ldc).
// EPI 2: relu(v+bias[n]) scatter to (spk,b,c,l), float4.
// EPI 3: split store (n<512 -> C, else C2 at n-512; both row stride 512).
// EPI 4: n<512: softplus(v+bias[n]) -> C (stride 512); 512<=n<544: -> C2 (stride 32); else skip.
#define LDSROW 40
template <int EPI>
__global__ __launch_bounds__(256) void gemm_mfma(const float* __restrict__ A, int lda,
                                                 const float* __restrict__ W,
                                                 float* __restrict__ C, float* __restrict__ C2,
                                                 int ldc, int K, const float* __restrict__ bias) {
  __shared__ unsigned short Ah[128 * LDSROW], Al[128 * LDSROW];
  __shared__ unsigned short Wh[128 * LDSROW], Wl[128 * LDSROW];
  int tid = threadIdx.x;
  int w = tid >> 6, L = tid & 63;
  int q = L >> 4, r16 = L & 15;
  int wm = (w >> 1) * 64, wn = (w & 1) * 64;
  long m0 = (long)blockIdx.y * 128, n0 = (long)blockIdx.x * 128;
  float4v acc[4][4];
#pragma unroll
  for (int i = 0; i < 4; ++i)
#pragma unroll
    for (int j = 0; j < 4; ++j) acc[i][j] = (float4v){0.f, 0.f, 0.f, 0.f};

  int lrow = tid >> 3;
  int lchunk = (tid & 7) * 4;

  for (int k0 = 0; k0 < K; k0 += 32) {
#pragma unroll
    for (int p = 0; p < 4; ++p) {
      int row = lrow + p * 32;
      float4v av = *(const float4v*)&A[(m0 + row) * lda + k0 + lchunk];
      float4v wv = *(const float4v*)&W[(n0 + row) * K + k0 + lchunk];
      ushort4v ahv, alv, whv, wlv;
#pragma unroll
      for (int e = 0; e < 4; ++e) {
        unsigned short h = f2bf_rn(av[e]);
        ahv[e] = h;
        alv[e] = f2bf_rn(av[e] - bf2f(h));
        h = f2bf_rn(wv[e]);
        whv[e] = h;
        wlv[e] = f2bf_rn(wv[e] - bf2f(h));
      }
      *(ushort4v*)&Ah[row * LDSROW + lchunk] = ahv;
      *(ushort4v*)&Al[row * LDSROW + lchunk] = alv;
      *(ushort4v*)&Wh[row * LDSROW + lchunk] = whv;
      *(ushort4v*)&Wl[row * LDSROW + lchunk] = wlv;
    }
    __syncthreads();
    short8 ah[4], al[4], bh[4], bl[4];
#pragma unroll
    for (int i = 0; i < 4; ++i) {
      int mr = wm + i * 16 + r16;
      ah[i] = *(const short8*)&Ah[mr * LDSROW + q * 8];
      al[i] = *(const short8*)&Al[mr * LDSROW + q * 8];
    }
#pragma unroll
    for (int j = 0; j < 4; ++j) {
      int nr = wn + j * 16 + r16;
      bh[j] = *(const short8*)&Wh[nr * LDSROW + q * 8];
      bl[j] = *(const short8*)&Wl[nr * LDSROW + q * 8];
    }
#pragma unroll
    for (int i = 0; i < 4; ++i)
#pragma unroll
      for (int j = 0; j < 4; ++j) {
        acc[i][j] = __builtin_amdgcn_mfma_f32_16x16x32_bf16(ah[i], bh[j], acc[i][j], 0, 0, 0);
        acc[i][j] = __builtin_amdgcn_mfma_f32_16x16x32_bf16(al[i], bh[j], acc[i][j], 0, 0, 0);
        acc[i][j] = __builtin_amdgcn_mfma_f32_16x16x32_bf16(ah[i], bl[j], acc[i][j], 0, 0, 0);
      }
    __syncthreads();
  }

  // D layout (16x16x32): row = q*4 + r, col = r16
#pragma unroll
  for (int i = 0; i < 4; ++i) {
    int m = (int)m0 + wm + i * 16 + q * 4;
#pragma unroll
    for (int j = 0; j < 4; ++j) {
      int n = (int)n0 + wn + j * 16 + r16;
      if (EPI == 0) {
#pragma unroll
        for (int r = 0; r < 4; ++r) C[(long)(m + r) * ldc + n] = acc[i][j][r];
      } else if (EPI == 3) {
        float* dst = (n < 512) ? C : C2;
        int nn = n & 511;
#pragma unroll
        for (int r = 0; r < 4; ++r) dst[(long)(m + r) * 512 + nn] = acc[i][j][r];
      } else if (EPI == 4) {
        if (n < 512) {
          float vb = bias[n];
#pragma unroll
          for (int r = 0; r < 4; ++r) {
            float t = acc[i][j][r] + vb;
            t = (t > 20.f) ? t : __logf(1.f + __expf(t));
            C[(long)(m + r) * 512 + n] = t;
          }
        } else if (n < 544) {
#pragma unroll
          for (int r = 0; r < 4; ++r) C2[(long)(m + r) * 32 + (n - 512)] = acc[i][j][r];
        }
      } else {  // EPI == 2
        float vb = bias[n];
        int spk = n >> 8, c = n & 255;
        int b = m >> 11, l = m & 2047;
        float4v v;
#pragma unroll
        for (int r = 0; r < 4; ++r) {
          float t = acc[i][j][r] + vb;
          v[r] = t > 0.f ? t : 0.f;
        }
        *(float4v*)&C[(((long)(spk * BATCH + b)) * CIN + c) * L_SEQ + l] = v;
      }
    }
  }
}

// ---------------- depthwise causal conv(4) + bias + SiLU (reads xr, stride 512) ----------------
__global__ __launch_bounds__(256) void conv_silu(const float* __restrict__ xr,
                                                 const float* __restrict__ cw,
                                                 const float* __restrict__ cb,
                                                 float* __restrict__ xc) {
  int idx = blockIdx.x * 256 + threadIdx.x;
  int d = idx & 511;
  int ml = idx >> 9;
  int l = ml & 2047;
  float acc = cb[d];
  const float* w = cw + d * 4;
#pragma unroll
  for (int k = 0; k < 4; ++k) {
    int ll = l + k - 3;
    if (ll >= 0) acc += w[k] * xr[(long)(ml + k - 3) * 512 + d];
  }
  xc[(long)ml * 512 + d] = acc / (1.f + __expf(-acc));
}

// ---------------- chunked selective scan: thread per (b,d), 16 states in registers ------------
// bc: (M_ROWS, 32) — cols 0..15 = B, 16..31 = C
__global__ __launch_bounds__(256) void scan_pass1(const float* __restrict__ delta,
                                                  const float* __restrict__ xc,
                                                  const float* __restrict__ bc,
                                                  const float* __restrict__ A_log,
                                                  float* __restrict__ P,
                                                  float* __restrict__ Hl) {
  int b = blockIdx.z, c = blockIdx.y;
  int tid = threadIdx.x;
  int d = blockIdx.x * 256 + tid;
  __shared__ float sBC[LC][32];
  const long base = (long)b * L_SEQ + (long)c * LC;
  ((float4v*)sBC)[tid] = ((const float4v*)&bc[base * 32])[tid];  // LC*32 = 1024 floats
  float Aval[16];
  {
    float4v a[4];
#pragma unroll
    for (int g = 0; g < 4; ++g) a[g] = *(const float4v*)&A_log[d * 16 + g * 4];
#pragma unroll
    for (int s = 0; s < 16; ++s) Aval[s] = -__expf(a[s >> 2][s & 3]);
  }
  __syncthreads();
  float h[16];
#pragma unroll
  for (int s = 0; s < 16; ++s) h[s] = 0.f;
  float sd = 0.f;
#pragma unroll 4
  for (int t = 0; t < LC; ++t) {
    float dlv = delta[(base + t) * 512 + d];
    float xv = xc[(base + t) * 512 + d];
    float w = dlv * xv;
    sd += dlv;
    float4v Bv[4];
#pragma unroll
    for (int g = 0; g < 4; ++g) Bv[g] = *(const float4v*)&sBC[t][g * 4];
#pragma unroll
    for (int s = 0; s < 16; ++s) {
      float dA = __expf(dlv * Aval[s]);
      h[s] = dA * h[s] + w * Bv[s >> 2][s & 3];
    }
  }
  long idx = (((long)b * NC + c) * 512 + d) * 16;
#pragma unroll
  for (int g = 0; g < 4; ++g) {
    float4v pv, hv;
#pragma unroll
    for (int e = 0; e < 4; ++e) {
      pv[e] = __expf(Aval[g * 4 + e] * sd);
      hv[e] = h[g * 4 + e];
    }
    *(float4v*)&P[idx + g * 4] = pv;
    *(float4v*)&Hl[idx + g * 4] = hv;
  }
}

__global__ __launch_bounds__(256) void scan_combine(const float* __restrict__ P,
                                                    const float* __restrict__ Hl,
                                                    float* __restrict__ H0) {
  int idx = blockIdx.x * 256 + threadIdx.x;  // over B*512*16 = 65536
  int b = idx >> 13;
  int ds = idx & 8191;
  float h = 0.f;
#pragma unroll 8
  for (int c = 0; c < NC; ++c) {
    long off = (((long)b * NC + c) << 13) + ds;
    H0[off] = h;
    h = P[off] * h + Hl[off];
  }
}

__global__ __launch_bounds__(256) void scan_pass2(const float* __restrict__ delta,
                                                  float* __restrict__ y,
                                                  const float* __restrict__ xc,
                                                  const float* __restrict__ bc,
                                                  const float* __restrict__ z,
                                                  const float* __restrict__ A_log,
                                                  const float* __restrict__ Dp,
                                                  const float* __restrict__ H0) {
  int b = blockIdx.z, c = blockIdx.y;
  int tid = threadIdx.x;
  int d = blockIdx.x * 256 + tid;
  __shared__ float sBC[LC][32];
  const long base = (long)b * L_SEQ + (long)c * LC;
  ((float4v*)sBC)[tid] = ((const float4v*)&bc[base * 32])[tid];
  float Aval[16];
  {
    float4v a[4];
#pragma unroll
    for (int g = 0; g < 4; ++g) a[g] = *(const float4v*)&A_log[d * 16 + g * 4];
#pragma unroll
    for (int s = 0; s < 16; ++s) Aval[s] = -__expf(a[s >> 2][s & 3]);
  }
  float Dval = Dp[d];
  float h[16];
  {
    long hidx = (((long)b * NC + c) * 512 + d) * 16;
#pragma unroll
    for (int g = 0; g < 4; ++g) {
      float4v hv = *(const float4v*)&H0[hidx + g * 4];
#pragma unroll
      for (int e = 0; e < 4; ++e) h[g * 4 + e] = hv[e];
    }
  }
  __syncthreads();
#pragma unroll 4
  for (int t = 0; t < LC; ++t) {
    float dlv = delta[(base + t) * 512 + d];
    float xv = xc[(base + t) * 512 + d];
    float zv = z[(base + t) * 512 + d];
    float w = dlv * xv;
    float4v Bv[4], Cv[4];
#pragma unroll
    for (int g = 0; g < 4; ++g) {
      Bv[g] = *(const float4v*)&sBC[t][g * 4];
      Cv[g] = *(const float4v*)&sBC[t][16 + g * 4];
    }
    float ya = 0.f, yb = 0.f, yc2 = 0.f, yd = 0.f;
#pragma unroll
    for (int s = 0; s < 4; ++s) {
      float dA = __expf(dlv * Aval[s]);
      h[s] = dA * h[s] + w * Bv[0][s];
      ya += h[s] * Cv[0][s];
    }
#pragma unroll
    for (int s = 4; s < 8; ++s) {
      float dA = __expf(dlv * Aval[s]);
      h[s] = dA * h[s] + w * Bv[1][s - 4];
      yb += h[s] * Cv[1][s - 4];
    }
#pragma unroll
    for (int s = 8; s < 12; ++s) {
      float dA = __expf(dlv * Aval[s]);
      h[s] = dA * h[s] + w * Bv[2][s - 8];
      yc2 += h[s] * Cv[2][s - 8];
    }
#pragma unroll
    for (int s = 12; s < 16; ++s) {
      float dA = __expf(dlv * Aval[s]);
      h[s] = dA * h[s] + w * Bv[3][s - 12];
      yd += h[s] * Cv[3][s - 12];
    }
    float yv = (ya + yb) + (yc2 + yd);
    float yf = (yv + xv * Dval) * (zv / (1.f + __expf(-zv)));
    y[(base + t) * 512 + d] = yf;
  }
}

extern "C" void kernel_launch(void* const* d_in, const int* in_sizes, int n_in, void* d_out,
                              int out_size, void* d_ws, size_t ws_size, hipStream_t stream) {
  const float* input = (const float*)d_in[0];
  const float* in_proj_w = (const float*)d_in[1];
  const float* conv_w = (const float*)d_in[2];
  const float* conv_b = (const float*)d_in[3];
  const float* x_proj_w = (const float*)d_in[4];
  const float* dt_proj_w = (const float*)d_in[5];
  const float* dt_proj_b = (const float*)d_in[6];
  const float* A_log = (const float*)d_in[7];
  const float* Dp = (const float*)d_in[8];
  const float* out_proj_w = (const float*)d_in[9];
  const float* out_lin_w = (const float*)d_in[10];
  const float* out_lin_b = (const float*)d_in[11];

  char* ws = (char*)d_ws;
  float* buf_x = (float*)(ws);                // 16 MB: layer in/out  (H0 aliases during scan)
  float* buf_xr = (float*)(ws + 16777216);    // 32 MB: xr  (P/Hl alias after conv)
  float* buf_z = (float*)(ws + 50331648);     // 32 MB: z
  float* buf_xc = (float*)(ws + 83886080);    // 32 MB: conv+silu out
  float* buf_bc = (float*)(ws + 117440512);   // 2 MB: B,C (M_ROWS x 32)
  float* buf_wc = (float*)(ws + 119537664);   // 1 MB: W_comb (512 x 512)
  float* buf_dy = (float*)(ws + 120586240);   // 32 MB: delta, then y in-place
  float* buf_wd0 = (float*)(ws + 154140672);  // 1.31 MB: Wd layer 0 (640 x 512)
  float* buf_wd1 = (float*)(ws + 155451392);  // 1.31 MB: Wd layer 1
  float* buf_P = buf_xr;                      // 16 MB
  float* buf_Hl = buf_xr + (4 << 20);         // 16 MB
  float* buf_H0 = buf_x;                      // 16 MB

  build_wd<<<dim3(2, 640), 256, 0, stream>>>(x_proj_w, dt_proj_w, buf_wd0);
  build_wd<<<dim3(2, 640), 256, 0, stream>>>(x_proj_w + 48 * 512, dt_proj_w + 512 * 16, buf_wd1);
  build_wcomb<<<dim3(2, 512), 256, 0, stream>>>(out_lin_w, out_proj_w + (long)256 * 512, buf_wc);
  transpose_in<<<dim3(64, 8, 8), dim3(32, 8), 0, stream>>>(input, buf_x);

  for (int i = 0; i < 2; ++i) {
    gemm_mfma<3><<<dim3(8, 128), 256, 0, stream>>>(buf_x, 256, in_proj_w + (long)i * 1024 * 256,
                                                   buf_xr, buf_z, 512, 256, nullptr);
    conv_silu<<<32768, 256, 0, stream>>>(buf_xr, conv_w + i * 512 * 4, conv_b + i * 512, buf_xc);
    gemm_mfma<4><<<dim3(5, 128), 256, 0, stream>>>(buf_xc, 512, (i == 0) ? buf_wd0 : buf_wd1,
                                                   buf_dy, buf_bc, 512, 512,
                                                   dt_proj_b + i * 512);
    scan_pass1<<<dim3(2, NC, 8), 256, 0, stream>>>(buf_dy, buf_xc, buf_bc,
                                                   A_log + (long)i * 512 * 16, buf_P, buf_Hl);
    scan_combine<<<256, 256, 0, stream>>>(buf_P, buf_Hl, buf_H0);
    scan_pass2<<<dim3(2, NC, 8), 256, 0, stream>>>(buf_dy, buf_dy, buf_xc, buf_bc, buf_z,
                                                   A_log + (long)i * 512 * 16, Dp + i * 512,
                                                   buf_H0);
    if (i == 0) {
      gemm_mfma<0><<<dim3(2, 128), 256, 0, stream>>>(buf_dy, 512, out_proj_w, buf_x, nullptr, 256,
                                                     512, nullptr);
    } else {
      gemm_mfma<2><<<dim3(4, 128), 256, 0, stream>>>(buf_dy, 512, buf_wc, (float*)d_out, nullptr,
                                                     0, 512, out_lin_b);
    }
  }
}

// Round 6
// 627.978 us; speedup vs baseline: 3.2404x; 1.0845x over previous
//
#include <hip/hip_runtime.h>
#include <cmath>

#define L_SEQ 2048
#define BATCH 8
#define CIN 256
#define DIN 512
#define M_ROWS (BATCH * L_SEQ)  // 16384
#define NC 64                   // scan chunks
#define LC 32                   // chunk length

typedef __attribute__((ext_vector_type(8))) short short8;
typedef __attribute__((ext_vector_type(4))) float float4v;
typedef __attribute__((ext_vector_type(4))) unsigned short ushort4v;
typedef __attribute__((ext_vector_type(4))) unsigned int uint4v;

__device__ inline unsigned short f2bf_rn(float x) {
  union { float f; unsigned u; } v;
  v.f = x;
  unsigned r = v.u + 0x7FFF + ((v.u >> 16) & 1);
  return (unsigned short)(r >> 16);
}
__device__ inline float bf2f(unsigned short h) {
  union { unsigned u; float f; } v;
  v.u = ((unsigned)h) << 16;
  return v.f;
}
// packed bf16 pair: hi (round-nearest) in top 16, lo (residual) in low 16
__device__ inline unsigned pack_split(float x) {
  unsigned short h = f2bf_rn(x);
  unsigned short l = f2bf_rn(x - bf2f(h));
  return (((unsigned)h) << 16) | l;
}
__device__ inline float unpack_f(unsigned p) {
  return bf2f((unsigned short)(p >> 16)) + bf2f((unsigned short)(p & 0xffff));
}

// ---------------- transpose (B,C,L) -> (B,L,C), packed ----------------
__global__ __launch_bounds__(256) void transpose_in(const float* __restrict__ in,
                                                    unsigned* __restrict__ out) {
  __shared__ float tile[32][33];
  int b = blockIdx.z;
  int l0 = blockIdx.x * 32, c0 = blockIdx.y * 32;
  int tx = threadIdx.x, ty = threadIdx.y;  // 32 x 8
#pragma unroll
  for (int k = 0; k < 4; ++k)
    tile[ty + k * 8][tx] = in[(long)(b * CIN + c0 + ty + k * 8) * L_SEQ + l0 + tx];
  __syncthreads();
#pragma unroll
  for (int k = 0; k < 4; ++k)
    out[(long)(b * L_SEQ + l0 + ty + k * 8) * CIN + c0 + tx] = pack_split(tile[tx][ty + k * 8]);
}

// ---------------- weight packing ----------------
__global__ __launch_bounds__(256) void split_pack(const float* __restrict__ in,
                                                  unsigned* __restrict__ out, int n) {
  int i = blockIdx.x * 256 + threadIdx.x;
  if (i < n) out[i] = pack_split(in[i]);
}

// Wd (640 x 512): rows 0..511 = dt_proj_w @ x_proj_w[0:16]; 512..543 = B,C rows; rest 0
__global__ __launch_bounds__(256) void build_wd(const float* __restrict__ xpw,
                                                const float* __restrict__ dtw,
                                                unsigned* __restrict__ Wd) {
  int k = blockIdx.x * 256 + threadIdx.x;  // 0..511
  int n = blockIdx.y;                      // 0..639
  float v;
  if (n < 512) {
    v = 0.f;
#pragma unroll
    for (int r = 0; r < 16; ++r) v += dtw[n * 16 + r] * xpw[r * 512 + k];
  } else if (n < 544) {
    v = xpw[(16 + n - 512) * 512 + k];
  } else {
    v = 0.f;
  }
  Wd[(long)n * 512 + k] = pack_split(v);
}

// W_comb (512 x 512): out_lin_w (512x256) @ out_proj_w[layer1] (256x512)
__global__ __launch_bounds__(256) void build_wcomb(const float* __restrict__ olw,
                                                   const float* __restrict__ opw,
                                                   unsigned* __restrict__ Wc) {
  int d = blockIdx.x * 256 + threadIdx.x;  // 0..511
  int o = blockIdx.y;                      // 0..511
  float v = 0.f;
#pragma unroll 4
  for (int c = 0; c < 256; ++c) v += olw[o * 256 + c] * opw[(long)c * 512 + d];
  Wc[(long)o * 512 + d] = pack_split(v);
}

// ---------------- bf16x3 MFMA GEMM on packed operands ----------------
// C[m,n] = sum_k A[m,k]*W[n,k], A/W packed (hi<<16|lo).
// EPI 2: relu(v+bias[n]) scatter to (spk,b,c,l) fp32.
// EPI 3: split fp32 store: n<512 -> C (stride 512) = xr; else C2 (stride 512) = z.
// EPI 4: n<512: softplus(v+bias[n]) -> C (stride 512); 512<=n<544 -> C2 (stride 32); else skip.
// EPI 5: packed store -> Cp (stride 256).
#define LDSROW 40
template <int EPI>
__global__ __launch_bounds__(256) void gemm_mfma(const unsigned* __restrict__ A, int lda,
                                                 const unsigned* __restrict__ W,
                                                 float* __restrict__ C, float* __restrict__ C2,
                                                 unsigned* __restrict__ Cp, int K,
                                                 const float* __restrict__ bias) {
  __shared__ unsigned short Ah[128 * LDSROW], Al[128 * LDSROW];
  __shared__ unsigned short Wh[128 * LDSROW], Wl[128 * LDSROW];
  int tid = threadIdx.x;
  int w = tid >> 6, L = tid & 63;
  int q = L >> 4, r16 = L & 15;
  int wm = (w >> 1) * 64, wn = (w & 1) * 64;
  long m0 = (long)blockIdx.y * 128, n0 = (long)blockIdx.x * 128;
  float4v acc[4][4];
#pragma unroll
  for (int i = 0; i < 4; ++i)
#pragma unroll
    for (int j = 0; j < 4; ++j) acc[i][j] = (float4v){0.f, 0.f, 0.f, 0.f};

  int lrow = tid >> 3;
  int lchunk = (tid & 7) * 4;

  for (int k0 = 0; k0 < K; k0 += 32) {
#pragma unroll
    for (int p = 0; p < 4; ++p) {
      int row = lrow + p * 32;
      uint4v av = *(const uint4v*)&A[(m0 + row) * lda + k0 + lchunk];
      uint4v wv = *(const uint4v*)&W[(n0 + row) * K + k0 + lchunk];
      ushort4v ahv, alv, whv, wlv;
#pragma unroll
      for (int e = 0; e < 4; ++e) {
        ahv[e] = (unsigned short)(av[e] >> 16);
        alv[e] = (unsigned short)(av[e] & 0xffff);
        whv[e] = (unsigned short)(wv[e] >> 16);
        wlv[e] = (unsigned short)(wv[e] & 0xffff);
      }
      *(ushort4v*)&Ah[row * LDSROW + lchunk] = ahv;
      *(ushort4v*)&Al[row * LDSROW + lchunk] = alv;
      *(ushort4v*)&Wh[row * LDSROW + lchunk] = whv;
      *(ushort4v*)&Wl[row * LDSROW + lchunk] = wlv;
    }
    __syncthreads();
    short8 ah[4], al[4], bh[4], bl[4];
#pragma unroll
    for (int i = 0; i < 4; ++i) {
      int mr = wm + i * 16 + r16;
      ah[i] = *(const short8*)&Ah[mr * LDSROW + q * 8];
      al[i] = *(const short8*)&Al[mr * LDSROW + q * 8];
    }
#pragma unroll
    for (int j = 0; j < 4; ++j) {
      int nr = wn + j * 16 + r16;
      bh[j] = *(const short8*)&Wh[nr * LDSROW + q * 8];
      bl[j] = *(const short8*)&Wl[nr * LDSROW + q * 8];
    }
#pragma unroll
    for (int i = 0; i < 4; ++i)
#pragma unroll
      for (int j = 0; j < 4; ++j) {
        acc[i][j] = __builtin_amdgcn_mfma_f32_16x16x32_bf16(ah[i], bh[j], acc[i][j], 0, 0, 0);
        acc[i][j] = __builtin_amdgcn_mfma_f32_16x16x32_bf16(al[i], bh[j], acc[i][j], 0, 0, 0);
        acc[i][j] = __builtin_amdgcn_mfma_f32_16x16x32_bf16(ah[i], bl[j], acc[i][j], 0, 0, 0);
      }
    __syncthreads();
  }

  // D layout (16x16x32): row = q*4 + r, col = r16
#pragma unroll
  for (int i = 0; i < 4; ++i) {
    int m = (int)m0 + wm + i * 16 + q * 4;
#pragma unroll
    for (int j = 0; j < 4; ++j) {
      int n = (int)n0 + wn + j * 16 + r16;
      if (EPI == 3) {
        float* dst = (n < 512) ? C : C2;
        int nn = n & 511;
#pragma unroll
        for (int r = 0; r < 4; ++r) dst[(long)(m + r) * 512 + nn] = acc[i][j][r];
      } else if (EPI == 4) {
        if (n < 512) {
          float vb = bias[n];
#pragma unroll
          for (int r = 0; r < 4; ++r) {
            float t = acc[i][j][r] + vb;
            t = (t > 20.f) ? t : __logf(1.f + __expf(t));
            C[(long)(m + r) * 512 + n] = t;
          }
        } else if (n < 544) {
#pragma unroll
          for (int r = 0; r < 4; ++r) C2[(long)(m + r) * 32 + (n - 512)] = acc[i][j][r];
        }
      } else if (EPI == 5) {
#pragma unroll
        for (int r = 0; r < 4; ++r) Cp[(long)(m + r) * 256 + n] = pack_split(acc[i][j][r]);
      } else {  // EPI == 2
        float vb = bias[n];
        int spk = n >> 8, c = n & 255;
        int b = m >> 11, l = m & 2047;
        float4v v;
#pragma unroll
        for (int r = 0; r < 4; ++r) {
          float t = acc[i][j][r] + vb;
          v[r] = t > 0.f ? t : 0.f;
        }
        *(float4v*)&C[(((long)(spk * BATCH + b)) * CIN + c) * L_SEQ + l] = v;
      }
    }
  }
}

// ---------------- depthwise causal conv(4) + bias + SiLU -> packed xc ----------------
__global__ __launch_bounds__(256) void conv_silu(const float* __restrict__ xr,
                                                 const float* __restrict__ cw,
                                                 const float* __restrict__ cb,
                                                 unsigned* __restrict__ xcp) {
  int idx = blockIdx.x * 256 + threadIdx.x;
  int d = idx & 511;
  int ml = idx >> 9;
  int l = ml & 2047;
  float acc = cb[d];
  const float* w = cw + d * 4;
#pragma unroll
  for (int k = 0; k < 4; ++k) {
    int ll = l + k - 3;
    if (ll >= 0) acc += w[k] * xr[(long)(ml + k - 3) * 512 + d];
  }
  xcp[(long)ml * 512 + d] = pack_split(acc / (1.f + __expf(-acc)));
}

// ---------------- chunked selective scan: thread per (b,d), 16 states in registers ------------
__global__ __launch_bounds__(256) void scan_pass1(const float* __restrict__ delta,
                                                  const unsigned* __restrict__ xcp,
                                                  const float* __restrict__ bc,
                                                  const float* __restrict__ A_log,
                                                  float* __restrict__ P,
                                                  float* __restrict__ Hl) {
  int b = blockIdx.z, c = blockIdx.y;
  int tid = threadIdx.x;
  int d = blockIdx.x * 256 + tid;
  __shared__ float sBC[LC][32];
  const long base = (long)b * L_SEQ + (long)c * LC;
  ((float4v*)sBC)[tid] = ((const float4v*)&bc[base * 32])[tid];
  float Aval[16];
  {
    float4v a[4];
#pragma unroll
    for (int g = 0; g < 4; ++g) a[g] = *(const float4v*)&A_log[d * 16 + g * 4];
#pragma unroll
    for (int s = 0; s < 16; ++s) Aval[s] = -__expf(a[s >> 2][s & 3]);
  }
  __syncthreads();
  float h[16];
#pragma unroll
  for (int s = 0; s < 16; ++s) h[s] = 0.f;
  float sd = 0.f;
#pragma unroll 4
  for (int t = 0; t < LC; ++t) {
    float dlv = delta[(base + t) * 512 + d];
    float xv = unpack_f(xcp[(base + t) * 512 + d]);
    float w = dlv * xv;
    sd += dlv;
    float4v Bv[4];
#pragma unroll
    for (int g = 0; g < 4; ++g) Bv[g] = *(const float4v*)&sBC[t][g * 4];
#pragma unroll
    for (int s = 0; s < 16; ++s) {
      float dA = __expf(dlv * Aval[s]);
      h[s] = dA * h[s] + w * Bv[s >> 2][s & 3];
    }
  }
  long idx = (((long)b * NC + c) * 512 + d) * 16;
#pragma unroll
  for (int g = 0; g < 4; ++g) {
    float4v pv, hv;
#pragma unroll
    for (int e = 0; e < 4; ++e) {
      pv[e] = __expf(Aval[g * 4 + e] * sd);
      hv[e] = h[g * 4 + e];
    }
    *(float4v*)&P[idx + g * 4] = pv;
    *(float4v*)&Hl[idx + g * 4] = hv;
  }
}

__global__ __launch_bounds__(256) void scan_combine(const float* __restrict__ P,
                                                    const float* __restrict__ Hl,
                                                    float* __restrict__ H0) {
  int idx = blockIdx.x * 256 + threadIdx.x;  // over B*512*16 = 65536
  int b = idx >> 13;
  int ds = idx & 8191;
  float h = 0.f;
#pragma unroll 8
  for (int c = 0; c < NC; ++c) {
    long off = (((long)b * NC + c) << 13) + ds;
    H0[off] = h;
    h = P[off] * h + Hl[off];
  }
}

// writes packed y in-place over delta (same element slots)
__global__ __launch_bounds__(256) void scan_pass2(const float* __restrict__ delta,
                                                  unsigned* __restrict__ y,
                                                  const unsigned* __restrict__ xcp,
                                                  const float* __restrict__ bc,
                                                  const float* __restrict__ z,
                                                  const float* __restrict__ A_log,
                                                  const float* __restrict__ Dp,
                                                  const float* __restrict__ H0) {
  int b = blockIdx.z, c = blockIdx.y;
  int tid = threadIdx.x;
  int d = blockIdx.x * 256 + tid;
  __shared__ float sBC[LC][32];
  const long base = (long)b * L_SEQ + (long)c * LC;
  ((float4v*)sBC)[tid] = ((const float4v*)&bc[base * 32])[tid];
  float Aval[16];
  {
    float4v a[4];
#pragma unroll
    for (int g = 0; g < 4; ++g) a[g] = *(const float4v*)&A_log[d * 16 + g * 4];
#pragma unroll
    for (int s = 0; s < 16; ++s) Aval[s] = -__expf(a[s >> 2][s & 3]);
  }
  float Dval = Dp[d];
  float h[16];
  {
    long hidx = (((long)b * NC + c) * 512 + d) * 16;
#pragma unroll
    for (int g = 0; g < 4; ++g) {
      float4v hv = *(const float4v*)&H0[hidx + g * 4];
#pragma unroll
      for (int e = 0; e < 4; ++e) h[g * 4 + e] = hv[e];
    }
  }
  __syncthreads();
#pragma unroll 4
  for (int t = 0; t < LC; ++t) {
    float dlv = delta[(base + t) * 512 + d];
    float xv = unpack_f(xcp[(base + t) * 512 + d]);
    float zv = z[(base + t) * 512 + d];
    float w = dlv * xv;
    float4v Bv[4], Cv[4];
#pragma unroll
    for (int g = 0; g < 4; ++g) {
      Bv[g] = *(const float4v*)&sBC[t][g * 4];
      Cv[g] = *(const float4v*)&sBC[t][16 + g * 4];
    }
    float ya = 0.f, yb = 0.f, yc2 = 0.f, yd = 0.f;
#pragma unroll
    for (int s = 0; s < 4; ++s) {
      float dA = __expf(dlv * Aval[s]);
      h[s] = dA * h[s] + w * Bv[0][s];
      ya += h[s] * Cv[0][s];
    }
#pragma unroll
    for (int s = 4; s < 8; ++s) {
      float dA = __expf(dlv * Aval[s]);
      h[s] = dA * h[s] + w * Bv[1][s - 4];
      yb += h[s] * Cv[1][s - 4];
    }
#pragma unroll
    for (int s = 8; s < 12; ++s) {
      float dA = __expf(dlv * Aval[s]);
      h[s] = dA * h[s] + w * Bv[2][s - 8];
      yc2 += h[s] * Cv[2][s - 8];
    }
#pragma unroll
    for (int s = 12; s < 16; ++s) {
      float dA = __expf(dlv * Aval[s]);
      h[s] = dA * h[s] + w * Bv[3][s - 12];
      yd += h[s] * Cv[3][s - 12];
    }
    float yv = (ya + yb) + (yc2 + yd);
    float yf = (yv + xv * Dval) * (zv / (1.f + __expf(-zv)));
    y[(base + t) * 512 + d] = pack_split(yf);
  }
}

extern "C" void kernel_launch(void* const* d_in, const int* in_sizes, int n_in, void* d_out,
                              int out_size, void* d_ws, size_t ws_size, hipStream_t stream) {
  const float* input = (const float*)d_in[0];
  const float* in_proj_w = (const float*)d_in[1];
  const float* conv_w = (const float*)d_in[2];
  const float* conv_b = (const float*)d_in[3];
  const float* x_proj_w = (const float*)d_in[4];
  const float* dt_proj_w = (const float*)d_in[5];
  const float* dt_proj_b = (const float*)d_in[6];
  const float* A_log = (const float*)d_in[7];
  const float* Dp = (const float*)d_in[8];
  const float* out_proj_w = (const float*)d_in[9];
  const float* out_lin_w = (const float*)d_in[10];
  const float* out_lin_b = (const float*)d_in[11];

  char* ws = (char*)d_ws;
  unsigned* buf_x = (unsigned*)(ws);          // 16 MB: packed layer in/out (H0 aliases in scan)
  float* buf_xr = (float*)(ws + 16777216);    // 32 MB: xr fp32 (P/Hl alias after conv)
  float* buf_z = (float*)(ws + 50331648);     // 32 MB: z fp32
  unsigned* buf_xcp = (unsigned*)(ws + 83886080);  // 32 MB: packed conv+silu out
  float* buf_bc = (float*)(ws + 117440512);   // 2 MB: B,C fp32 (M_ROWS x 32)
  unsigned* buf_wc = (unsigned*)(ws + 119537664);  // 1 MB: packed W_comb
  float* buf_dy = (float*)(ws + 120586240);   // 32 MB: delta fp32, then packed y in-place
  unsigned* buf_wd0 = (unsigned*)(ws + 154140672);  // 1.31 MB: packed Wd layer 0
  unsigned* buf_wd1 = (unsigned*)(ws + 155451392);  // 1.31 MB: packed Wd layer 1
  unsigned* buf_wt = (unsigned*)(ws + 156762112);   // 1 MB: reusable packed weight scratch
  float* buf_P = buf_xr;                      // 16 MB
  float* buf_Hl = buf_xr + (4 << 20);         // 16 MB
  float* buf_H0 = (float*)buf_x;              // 16 MB
  unsigned* buf_y = (unsigned*)buf_dy;

  build_wd<<<dim3(2, 640), 256, 0, stream>>>(x_proj_w, dt_proj_w, buf_wd0);
  build_wd<<<dim3(2, 640), 256, 0, stream>>>(x_proj_w + 48 * 512, dt_proj_w + 512 * 16, buf_wd1);
  build_wcomb<<<dim3(2, 512), 256, 0, stream>>>(out_lin_w, out_proj_w + (long)256 * 512, buf_wc);
  transpose_in<<<dim3(64, 8, 8), dim3(32, 8), 0, stream>>>(input, buf_x);

  for (int i = 0; i < 2; ++i) {
    split_pack<<<1024, 256, 0, stream>>>(in_proj_w + (long)i * 1024 * 256, buf_wt, 1024 * 256);
    gemm_mfma<3><<<dim3(8, 128), 256, 0, stream>>>(buf_x, 256, buf_wt, buf_xr, buf_z, nullptr,
                                                   256, nullptr);
    conv_silu<<<32768, 256, 0, stream>>>(buf_xr, conv_w + i * 512 * 4, conv_b + i * 512, buf_xcp);
    gemm_mfma<4><<<dim3(5, 128), 256, 0, stream>>>(buf_xcp, 512, (i == 0) ? buf_wd0 : buf_wd1,
                                                   buf_dy, buf_bc, nullptr, 512,
                                                   dt_proj_b + i * 512);
    scan_pass1<<<dim3(2, NC, 8), 256, 0, stream>>>(buf_dy, buf_xcp, buf_bc,
                                                   A_log + (long)i * 512 * 16, buf_P, buf_Hl);
    scan_combine<<<256, 256, 0, stream>>>(buf_P, buf_Hl, buf_H0);
    scan_pass2<<<dim3(2, NC, 8), 256, 0, stream>>>(buf_dy, buf_y, buf_xcp, buf_bc, buf_z,
                                                   A_log + (long)i * 512 * 16, Dp + i * 512,
                                                   buf_H0);
    if (i == 0) {
      split_pack<<<512, 256, 0, stream>>>(out_proj_w, buf_wt, 256 * 512);
      gemm_mfma<5><<<dim3(2, 128), 256, 0, stream>>>(buf_y, 512, buf_wt, nullptr, nullptr, buf_x,
                                                     512, nullptr);
    } else {
      gemm_mfma<2><<<dim3(4, 128), 256, 0, stream>>>(buf_y, 512, buf_wc, (float*)d_out, nullptr,
                                                     nullptr, 512, out_lin_b);
    }
  }
}